// Round 4
// baseline (993.945 us; speedup 1.0000x reference)
//
#include <hip/hip_runtime.h>
#include <stdint.h>

// ---------------- problem constants ----------------
#define NNODE   150000
#define NNODE16 150016             // padded stride for deg copies
#define EDGES   4000000
#define NSEED   500
#define NSAMP   15000              // int(150000 * 0.1)
#define MOUT    12150000           // 3E + N : decoder output length
#define SENTK   0xFFFFFFFFFFFFFFFFULL
#define SPAN    150000ULL
#define MULTK   51616ULL           // ((2^32 % 150000)^2) % 150000
#define FIXED   8150000            // pairs (8M) + self loops (150k) fixed slots

// hash encoding: h = (r << 18) | c.  Order-preserving bijection of the
// reference's r*150000+c (both lexicographic in (r,c), c < 150000 < 2^18),
// so the sorted-unique sequence is identical while decode is shift/mask.
// Max value = 149999<<18 | 149999 < 2^36 -> exactly 4 x 9-bit radix passes.

// sort geometry: 8192-key chunks, one tile per block.
// NOTE (R5 post-mortem): LSD radix REQUIRES a stable per-pass scatter — the
// in-LDS 3x3-bit split below is what preserves lower-digit order across
// passes. Do not replace with atomic-rank placement.
// NOTE (R1 post-mortem, this session): do NOT fuse unique+final via a
// 1488-block ticketed lookback — agent-scope atomic spin traffic starved the
// kernel to 770 GB/s / 172 µs. Lookback is only safe at all-resident grid
// sizes with short walks (k_scan_lb, 186 blocks).
// NOTE (R3, this session): device-scope atomicAdd costs ~48-64B of fabric
// write per op (k_bfs1deg WRITE_SIZE=91MB for ~2M adds). Privatize by
// PHYSICAL XCD (HW_REG_XCC_ID) and use relaxed workgroup-scope atomics so
// the RMW stays in the XCD-local TCC.
#define CHUNK   8192
#define TH      512
#define NC      1488               // max chunks; multiple of 8 for XCD swizzle
#define NCX     (NC / 8)           // 186
#define MP      ((size_t)NC * CHUNK)
#define RADIX   512
#define NHIST   (RADIX * NC)       // 761,856
#define SNT     (NHIST / 4096)     // 186 lookback-scan tiles (exact)
#define NTILE   NC                 // uniq/final tiles == chunks

// enctail geometry
#define EBLK    2048
#define ENB     ((EDGES + EBLK - 1) / EBLK)   // 1954

// vectorized edge-pass geometry (4 edges/thread)
#define VNB     ((EDGES + 1023) / 1024)       // 3907

// masked-node compaction geometry
#define MTILE   2048
#define MB      ((NNODE + MTILE - 1) / MTILE)   // 74

// out layout (float32): [rows E][cols E][enc E][dec_rows M][dec_cols M][dec_vals M]
#define OUT_DR  12000000
#define OUT_DC  24150000
#define OUT_DV  36300000

// HW_REG_XCC_ID (id=20, offset=0, size=32): imm = 20 | (0<<6) | (31<<11)
#define XCCID_IMM 63508

// ---------------- threefry2x32 (JAX-exact, 20 rounds) ----------------
__host__ __device__ inline void tf2x32(uint32_t k0, uint32_t k1,
                                       uint32_t x0, uint32_t x1,
                                       uint32_t& o0, uint32_t& o1) {
  uint32_t ks2 = k0 ^ k1 ^ 0x1BD11BDAu;
  x0 += k0; x1 += k1;
#define TFR(d) { x0 += x1; x1 = (x1 << d) | (x1 >> (32 - d)); x1 ^= x0; }
  TFR(13) TFR(15) TFR(26) TFR(6)
  x0 += k1; x1 += ks2 + 1u;
  TFR(17) TFR(29) TFR(16) TFR(24)
  x0 += ks2; x1 += k0 + 2u;
  TFR(13) TFR(15) TFR(26) TFR(6)
  x0 += k0; x1 += k1 + 3u;
  TFR(17) TFR(29) TFR(16) TFR(24)
  x0 += k1; x1 += ks2 + 4u;
  TFR(13) TFR(15) TFR(26) TFR(6)
  x0 += ks2; x1 += k0 + 5u;
#undef TFR
  o0 = x0; o1 = x1;
}

__device__ inline unsigned long long tf_bits64(uint32_t k0, uint32_t k1, uint32_t i) {
  uint32_t o0, o1;
  tf2x32(k0, k1, 0u, i, o0, o1);
  return ((unsigned long long)o0 << 32) | o1;
}

// active chunk count (device, from tail append counter)
__device__ inline int activeChunks(const int* counters) {
  int m2 = FIXED + counters[2];
  return (m2 + CHUNK - 1) / CHUNK;
}

// ---------------- block primitives ----------------
__device__ inline int block_excl_scan_256(int v, int* lds /*>=5 ints*/, int& total) {
  int lane = threadIdx.x & 63, wid = threadIdx.x >> 6;
  int inc = v;
#pragma unroll
  for (int off = 1; off < 64; off <<= 1) {
    int y = __shfl_up(inc, off, 64);
    if (lane >= off) inc += y;
  }
  if (lane == 63) lds[wid] = inc;
  __syncthreads();
  if (threadIdx.x == 0) {
    int a = 0;
#pragma unroll
    for (int w = 0; w < 4; ++w) { int t = lds[w]; lds[w] = a; a += t; }
    lds[4] = a;
  }
  __syncthreads();
  total = lds[4];
  int res = inc - v + lds[wid];
  __syncthreads();
  return res;
}

// exclusive scan of 4 packed ints across 512 threads; aux >= 36 ints.
__device__ inline void scan512_x4(const int v[4], int ex[4], int tot[4], int* aux) {
  int lane = threadIdx.x & 63, wid = threadIdx.x >> 6;
  int inc[4];
#pragma unroll
  for (int j = 0; j < 4; ++j) inc[j] = v[j];
#pragma unroll
  for (int off = 1; off < 64; off <<= 1) {
#pragma unroll
    for (int j = 0; j < 4; ++j) {
      int y = __shfl_up(inc[j], off, 64);
      if (lane >= off) inc[j] += y;
    }
  }
  if (lane == 63) {
#pragma unroll
    for (int j = 0; j < 4; ++j) aux[j * 8 + wid] = inc[j];
  }
  __syncthreads();
  if (threadIdx.x == 0) {
#pragma unroll
    for (int j = 0; j < 4; ++j) {
      int a = 0;
#pragma unroll
      for (int w = 0; w < 8; ++w) { int t = aux[j * 8 + w]; aux[j * 8 + w] = a; a += t; }
      aux[32 + j] = a;
    }
  }
  __syncthreads();
#pragma unroll
  for (int j = 0; j < 4; ++j) {
    ex[j] = inc[j] - v[j] + aux[j * 8 + wid];
    tot[j] = aux[32 + j];
  }
}

__device__ inline int scan512_1(int v, int* aux /*>=9 ints*/) {
  int lane = threadIdx.x & 63, wid = threadIdx.x >> 6;
  int inc = v;
#pragma unroll
  for (int off = 1; off < 64; off <<= 1) {
    int y = __shfl_up(inc, off, 64);
    if (lane >= off) inc += y;
  }
  if (lane == 63) aux[wid] = inc;
  __syncthreads();
  if (threadIdx.x == 0) {
    int a = 0;
#pragma unroll
    for (int w = 0; w < 8; ++w) { int t = aux[w]; aux[w] = a; a += t; }
  }
  __syncthreads();
  return inc - v + aux[wid];
}

// wave-parallel decoupled-lookback: returns exclusive prefix for `tile` over
// packed state entries (bit31:30 = status {0 invalid,1 aggregate,2 prefix},
// bits 29:0 = value).  ONLY safe for all-resident grids (<=256 blocks) with
// short walks — see R1 post-mortem note above.
__device__ inline int lookback64(unsigned* state, int tile) {
  int lane = threadIdx.x;   // caller guarantees threadIdx.x < 64
  int acc = 0, cur = tile;
  for (;;) {
    int idx = cur - 1 - lane;
    unsigned v = 0;
    if (idx >= 0) {
      v = __hip_atomic_load(&state[idx], __ATOMIC_ACQUIRE, __HIP_MEMORY_SCOPE_AGENT);
      while ((v >> 30) == 0u)
        v = __hip_atomic_load(&state[idx], __ATOMIC_ACQUIRE, __HIP_MEMORY_SCOPE_AGENT);
    }
    unsigned st = (idx >= 0) ? (v >> 30) : 0u;
    int val = (int)(v & 0x3FFFFFFFu);
    unsigned long long pm = __ballot(st == 2u);
    int stop = pm ? (__ffsll((unsigned long long)pm) - 1) : 64;
    int contrib = (idx >= 0 && lane <= stop) ? val : 0;
#pragma unroll
    for (int off = 32; off; off >>= 1) contrib += __shfl_down(contrib, off, 64);
    acc += __shfl(contrib, 0, 64);           // broadcast so loop stays uniform
    if (stop < 64) break;
    cur -= 64;
  }
  return acc;
}

// LDS swizzle: rotate within 16-element rows to break 16-stride bank aliasing
__device__ inline int phys16(int p) { return (p & ~15) | ((p + (p >> 4)) & 15); }

// ---------------- BFS / enc kernels (fused) ----------------
__global__ __launch_bounds__(256) void k_seed(const int* seeds, uint8_t* frontier, uint8_t* masked) {
  int i = blockIdx.x * 256 + threadIdx.x;
  if (i < NSEED) { int v = seeds[i]; frontier[v] = 1; masked[v] = 1; }
}

// bfs hop 0 + rows/cols output copy; 4 edges/thread (MLP for the gathers).
// Writes alive[] fully (memset removed).
__global__ __launch_bounds__(256) void k_bfs0(const int* rows, const int* cols,
                                              const uint8_t* frontier, uint8_t* alive, uint8_t* nxt,
                                              float* out) {
  int g = blockIdx.x * 1024 + threadIdx.x * 4;
  if (g >= EDGES) return;
  if (g + 4 <= EDGES) {
    int4 r4 = *(const int4*)&rows[g];
    int4 c4 = *(const int4*)&cols[g];
    int rr[4] = {r4.x, r4.y, r4.z, r4.w};
    int cc[4] = {c4.x, c4.y, c4.z, c4.w};
    *(float4*)&out[g] = make_float4((float)rr[0], (float)rr[1], (float)rr[2], (float)rr[3]);
    *(float4*)&out[EDGES + g] = make_float4((float)cc[0], (float)cc[1], (float)cc[2], (float)cc[3]);
    uint8_t al[4];
#pragma unroll
    for (int k = 0; k < 4; ++k) {
      int hit = frontier[rr[k]] | frontier[cc[k]];
      al[k] = (uint8_t)(1 - hit);
      if (hit) { nxt[rr[k]] = 1; nxt[cc[k]] = 1; }
    }
    *(uchar4*)&alive[g] = make_uchar4(al[0], al[1], al[2], al[3]);
  } else {
    for (int e = g; e < EDGES; ++e) {
      int r = rows[e], c = cols[e];
      out[e] = (float)r;
      out[EDGES + e] = (float)c;
      int hit = frontier[r] | frontier[c];
      alive[e] = (uint8_t)(1 - hit);
      if (hit) { nxt[r] = 1; nxt[c] = 1; }
    }
  }
}

// bfs hop 1 + degree accumulation.
// R3: deg privatized by PHYSICAL XCD id (HW_REG_XCC_ID, measured 0-7 on
// MI355X) so each copy is only ever touched by one XCD; the atomic is then
// relaxed workgroup-scope -> RMW executes in the XCD-local TCC (L2), no
// cross-XCD fabric transaction, no per-op HBM write.  (R2 counters: the old
// device-scope adds cost 91MB WRITE_SIZE / ~90us for ~2M ops.)
// Inter-kernel visibility to k_dnorm = standard kernel-boundary L2 writeback.
__global__ __launch_bounds__(256) void k_bfs1deg(const int* rows, const int* cols,
                                                 const uint8_t* nxt, uint8_t* alive, int* deg8) {
  int g = blockIdx.x * 1024 + threadIdx.x * 4;
  if (g >= EDGES) return;
  int xcd = __builtin_amdgcn_s_getreg(XCCID_IMM) & 7;
  int* dmy = deg8 + xcd * NNODE16;
  if (g + 4 <= EDGES) {
    int4 r4 = *(const int4*)&rows[g];
    int4 c4 = *(const int4*)&cols[g];
    uchar4 a4 = *(const uchar4*)&alive[g];
    int rr[4] = {r4.x, r4.y, r4.z, r4.w};
    int cc[4] = {c4.x, c4.y, c4.z, c4.w};
    uint8_t aa[4] = {a4.x, a4.y, a4.z, a4.w};
    uint8_t na[4];
#pragma unroll
    for (int k = 0; k < 4; ++k) {
      int a = aa[k];
      if (a && (nxt[rr[k]] | nxt[cc[k]])) a = 0;
      na[k] = (uint8_t)a;
    }
    *(uchar4*)&alive[g] = make_uchar4(na[0], na[1], na[2], na[3]);
#pragma unroll
    for (int k = 0; k < 4; ++k)
      if (na[k])
        __hip_atomic_fetch_add(&dmy[rr[k]], 1, __ATOMIC_RELAXED,
                               __HIP_MEMORY_SCOPE_WORKGROUP);
  } else {
    for (int e = g; e < EDGES; ++e) {
      int a = alive[e];
      int r = rows[e];
      if (a && (nxt[r] | nxt[cols[e]])) { alive[e] = 0; a = 0; }
      if (a)
        __hip_atomic_fetch_add(&dmy[r], 1, __ATOMIC_RELAXED,
                               __HIP_MEMORY_SCOPE_WORKGROUP);
    }
  }
}

__global__ __launch_bounds__(256) void k_sample(uint8_t* masked,
                                                uint32_t a0, uint32_t a1, uint32_t b0, uint32_t b1) {
  int i = blockIdx.x * 256 + threadIdx.x;
  if (i >= NSAMP) return;
  unsigned long long hi = tf_bits64(a0, a1, (uint32_t)i);
  unsigned long long lo = tf_bits64(b0, b1, (uint32_t)i);
  unsigned long long off = ((hi % SPAN) * MULTK + (lo % SPAN)) % SPAN;
  masked[off] = 1;
}

// dnorm + fused masked|=nxt (R1: folds the old k_masked_or launch; nxt is
// final after k_bfs0, masked not read until k_mreduce -> ordering safe)
__global__ __launch_bounds__(256) void k_dnorm(const int* deg8, float* dnorm,
                                               uint8_t* masked, const uint8_t* nxt) {
  int v = blockIdx.x * 256 + threadIdx.x;
  if (v < NNODE) {
    int s = 0;
#pragma unroll
    for (int j = 0; j < 8; ++j) s += deg8[j * NNODE16 + v];
    float x = (float)s + 1e-12f;     // integer-valued sum is exact in f32
    dnorm[v] = (float)(1.0 / sqrt((double)x));
    masked[v] |= nxt[v];
  }
}

// encoder values + compacted tail-hash append.
// 2048 edges/block -> 1954 block-level atomics (same-address atomic service
// rate ~12ns was R4's 187us bottleneck at 15625 atomics).
__global__ __launch_bounds__(256) void k_enctail(const int* rows, const int* cols,
                                                 const uint8_t* alive, const float* dnorm,
                                                 float* out, unsigned long long* A, int* counters) {
  __shared__ int lds[8];
  __shared__ unsigned long long stage[EBLK];
  __shared__ int sbase;
  int base = blockIdx.x * EBLK;
  unsigned long long vv[8];
  int emit[8], c = 0;
#pragma unroll
  for (int k = 0; k < 8; ++k) {
    int e = base + k * 256 + threadIdx.x;
    emit[k] = 0;
    if (e < EDGES) {
      int r = rows[e], cc = cols[e];
      int a = alive[e];
      out[2 * EDGES + e] = a ? dnorm[r] * dnorm[cc] : 0.0f;
      unsigned long long v = ((unsigned long long)(unsigned)r << 18) | (unsigned)cc;
      if (a && v) { emit[k] = 1; vv[k] = v; c++; }
    }
  }
  int total;
  int ex = block_excl_scan_256(c, lds, total);
#pragma unroll
  for (int k = 0; k < 8; ++k) {
    if (emit[k]) stage[ex++] = vv[k];
  }
  if (threadIdx.x == 0) sbase = total ? atomicAdd(&counters[2], total) : 0;
  __syncthreads();
  int sb = sbase;
  for (int i = threadIdx.x; i < total; i += 256)
    A[(size_t)FIXED + sb + i] = stage[i];
}

// ---------------- masked-node compaction ----------------
__global__ __launch_bounds__(256) void k_mreduce(const uint8_t* masked, int* mPart) {
  __shared__ int lds[4];
  int base = blockIdx.x * MTILE;
  int s = 0;
  for (int i = threadIdx.x; i < MTILE; i += 256) {
    int idx = base + i;
    if (idx < NNODE) s += masked[idx];
  }
#pragma unroll
  for (int off = 32; off; off >>= 1) s += __shfl_down(s, off, 64);
  if ((threadIdx.x & 63) == 0) lds[threadIdx.x >> 6] = s;
  __syncthreads();
  if (threadIdx.x == 0) mPart[blockIdx.x] = lds[0] + lds[1] + lds[2] + lds[3];
}

__global__ __launch_bounds__(1024) void k_scan_small(int* part, int m, int* totalOut) {
  __shared__ int a[2048];
  int tid = threadIdx.x;
  a[tid] = (tid < m) ? part[tid] : 0;
  a[tid + 1024] = (tid + 1024 < m) ? part[tid + 1024] : 0;
  __syncthreads();
  for (int off = 1; off < 2048; off <<= 1) {
    int v1 = 0, v2;
    if (tid >= off) v1 = a[tid - off];
    v2 = a[tid + 1024 - off];
    __syncthreads();
    if (tid >= off) a[tid] += v1;
    a[tid + 1024] += v2;
    __syncthreads();
  }
  if (tid < m) part[tid] = (tid == 0) ? 0 : a[tid - 1];
  if (tid + 1024 < m) part[tid + 1024] = a[tid + 1023];
  if (tid == 0 && totalOut) *totalOut = a[2047];
}

__global__ __launch_bounds__(256) void k_mscatter(const uint8_t* masked, const int* mPart, int* mlist) {
  __shared__ int lds[8];
  int t0 = blockIdx.x * MTILE + threadIdx.x * 8;
  int c = 0;
#pragma unroll
  for (int k = 0; k < 8; ++k) { int idx = t0 + k; c += (idx < NNODE) ? masked[idx] : 0; }
  int total;
  int ex = block_excl_scan_256(c, lds, total);
  int run = mPart[blockIdx.x] + ex;
#pragma unroll
  for (int k = 0; k < 8; ++k) {
    int idx = t0 + k;
    if (idx < NNODE && masked[idx]) mlist[run++] = idx;
  }
}

// ---------------- hash building ----------------
// dead / zero hashes are written as 0 (not SENTK): zeros sort to the front,
// are never counted as uniques (prev inits to 0; hash 0 is handled by the +1).
__global__ __launch_bounds__(256) void k_build_pairs(const int* mlist, const int* counters,
                                                     unsigned long long* A,
                                                     uint32_t r0, uint32_t r1, uint32_t c0, uint32_t c1) {
  int e = blockIdx.x * 256 + threadIdx.x;
  long long tem = counters[1];
  unsigned long long bits = tf_bits64(r0, r1, (uint32_t)e);
  double u1 = __longlong_as_double((long long)((bits >> 12) | 0x3FF0000000000000ULL)) - 1.0;
  long long i1 = (long long)(u1 * (double)tem); if (i1 > tem - 1) i1 = tem - 1;
  bits = tf_bits64(c0, c1, (uint32_t)e);
  double u2 = __longlong_as_double((long long)((bits >> 12) | 0x3FF0000000000000ULL)) - 1.0;
  long long i2 = (long long)(u2 * (double)tem); if (i2 > tem - 1) i2 = tem - 1;
  unsigned long long tr = (unsigned long long)mlist[i1];
  unsigned long long tc = (unsigned long long)mlist[i2];
  A[2 * (size_t)e]     = (tr << 18) | tc;
  A[2 * (size_t)e + 1] = (tc << 18) | tr;
}

__global__ __launch_bounds__(256) void k_build_self(unsigned long long* A) {
  int v = blockIdx.x * 256 + threadIdx.x;
  if (v >= NNODE) return;
  unsigned long long u = (unsigned long long)v;
  A[2 * (size_t)EDGES + v] = (u << 18) | u;     // v=0 -> 0, fine
}

// pad [m2, AC*CHUNK) with sentinels (< CHUNK elements)
__global__ __launch_bounds__(256) void k_pad(unsigned long long* A, const int* counters) {
  int m2 = FIXED + counters[2];
  int ac = (m2 + CHUNK - 1) / CHUNK;
  size_t idx = (size_t)m2 + blockIdx.x * 256 + threadIdx.x;
  if (idx < (size_t)ac * CHUNK) A[idx] = SENTK;
}

// ---------------- LSD radix sort: 4 passes x 9 bits, 8192-key chunks ----------------
__global__ __launch_bounds__(TH) void k_rhist2(const unsigned long long* __restrict__ src,
                                               int* __restrict__ hist, int shift,
                                               const int* counters) {
  __shared__ int h8[RADIX * 4];
  int tid = threadIdx.x;
  int ac = activeChunks(counters);
  if ((int)blockIdx.x >= ac) { hist[(size_t)tid * NC + blockIdx.x] = 0; return; }
  for (int i = tid; i < RADIX * 4; i += TH) h8[i] = 0;
  __syncthreads();
  const ulonglong2* s2 = (const ulonglong2*)(src + (size_t)blockIdx.x * CHUNK);
  int rep = tid & 3, scnt = 0;
#pragma unroll
  for (int r = 0; r < 8; ++r) {
    ulonglong2 v = s2[tid + r * TH];
    int d0 = (int)((v.x >> shift) & (RADIX - 1));
    int d1 = (int)((v.y >> shift) & (RADIX - 1));
    if (d0 == RADIX - 1) scnt++; else atomicAdd(&h8[d0 * 4 + rep], 1);
    if (d1 == RADIX - 1) scnt++; else atomicAdd(&h8[d1 * 4 + rep], 1);
  }
  if (scnt) atomicAdd(&h8[(RADIX - 1) * 4 + rep], scnt);
  __syncthreads();
  int4 hv = *(const int4*)&h8[tid * 4];
  hist[(size_t)tid * NC + blockIdx.x] = hv.x + hv.y + hv.z + hv.w;
}

// single-kernel exclusive scan of hist (NHIST = 186 x 4096 ints) via
// decoupled lookback.  186 blocks of 256 threads are ALL resident on 256
// CUs simultaneously, so blockIdx-order spin-waits cannot deadlock and the
// walk terminates within <=3 rounds.  Replaces the 3-kernel
// reduce/small/apply chain (2 launches + 1 whole-GPU single-block bubble
// per radix pass).
__global__ __launch_bounds__(256) void k_scan_lb(int* __restrict__ g,
                                                 unsigned* __restrict__ tstate) {
  __shared__ int lds[8];
  __shared__ int sbase;
  int tile = blockIdx.x;
  int base = tile * 4096 + threadIdx.x * 16;
  int x[16];
  {
    int4 q0 = *(const int4*)&g[base];
    int4 q1 = *(const int4*)&g[base + 4];
    int4 q2 = *(const int4*)&g[base + 8];
    int4 q3 = *(const int4*)&g[base + 12];
    x[0]=q0.x; x[1]=q0.y; x[2]=q0.z;  x[3]=q0.w;
    x[4]=q1.x; x[5]=q1.y; x[6]=q1.z;  x[7]=q1.w;
    x[8]=q2.x; x[9]=q2.y; x[10]=q2.z; x[11]=q2.w;
    x[12]=q3.x; x[13]=q3.y; x[14]=q3.z; x[15]=q3.w;
  }
  int s = 0;
#pragma unroll
  for (int k = 0; k < 16; ++k) { int t = x[k]; x[k] = s; s += t; }
  int total;
  int ex = block_excl_scan_256(s, lds, total);
  if (threadIdx.x == 0) {
    unsigned st = (tile == 0) ? 0x80000000u : 0x40000000u;
    __hip_atomic_store(&tstate[tile], st | (unsigned)total,
                       __ATOMIC_RELEASE, __HIP_MEMORY_SCOPE_AGENT);
    if (tile == 0) sbase = 0;
  }
  if (tile > 0 && threadIdx.x < 64) {
    int acc = lookback64(tstate, tile);
    if (threadIdx.x == 0) {
      sbase = acc;
      __hip_atomic_store(&tstate[tile], 0x80000000u | (unsigned)(acc + total),
                         __ATOMIC_RELEASE, __HIP_MEMORY_SCOPE_AGENT);
    }
  }
  __syncthreads();
  int bb = sbase + ex;
#pragma unroll
  for (int k = 0; k < 16; ++k) x[k] += bb;
  *(int4*)&g[base]      = make_int4(x[0], x[1], x[2], x[3]);
  *(int4*)&g[base + 4]  = make_int4(x[4], x[5], x[6], x[7]);
  *(int4*)&g[base + 8]  = make_int4(x[8], x[9], x[10], x[11]);
  *(int4*)&g[base + 12] = make_int4(x[12], x[13], x[14], x[15]);
}

// STABLE scatter (required for LSD): 3x3-bit in-LDS split rounds sort the
// tile by the 9-bit digit while preserving intra-digit (= prior-pass) order,
// then a direct-addressed coalesced write per digit segment.
// R7: packed bit-field ranking. R8: keys held in a single u64 LDS array
// (halves the ds_read/ds_write instruction count vs the klo/khi split;
// phys16 on 8B elements spreads stride-16 walks over 16 bank-pairs = floor).
__global__ __launch_bounds__(TH) void k_rscatter2(const unsigned long long* __restrict__ src,
                                                  unsigned long long* __restrict__ dst,
                                                  const int* __restrict__ hist, int shift,
                                                  const int* counters) {
  __shared__ unsigned long long kk[CHUNK];
  __shared__ int h8[RADIX * 4];
  __shared__ int dstart[RADIX], gbase[RADIX];
  __shared__ int aux[40];
  int tid = threadIdx.x;
  // XCD-contiguous chunk swizzle: adjacent chunks on the same XCD, temporally adjacent
  int chunk = (blockIdx.x & 7) * NCX + (blockIdx.x >> 3);
  int ac = activeChunks(counters);
  if (chunk >= ac) return;
  size_t cbase = (size_t)chunk * CHUNK;
  gbase[tid] = hist[(size_t)tid * NC + chunk];
  for (int i = tid; i < RADIX * 4; i += TH) h8[i] = 0;
  __syncthreads();
  int rep = tid & 3;
  const ulonglong2* s2 = (const ulonglong2*)(src + cbase);
  int scnt = 0;
#pragma unroll
  for (int r = 0; r < 8; ++r) {
    ulonglong2 v = s2[tid + r * TH];
    int i = 2 * (tid + r * TH);
    kk[phys16(i)] = v.x;
    kk[phys16(i + 1)] = v.y;
    int d0 = (int)((v.x >> shift) & (RADIX - 1));
    int d1 = (int)((v.y >> shift) & (RADIX - 1));
    if (d0 == RADIX - 1) scnt++; else atomicAdd(&h8[d0 * 4 + rep], 1);
    if (d1 == RADIX - 1) scnt++; else atomicAdd(&h8[d1 * 4 + rep], 1);
  }
  if (scnt) atomicAdd(&h8[(RADIX - 1) * 4 + rep], scnt);
  __syncthreads();
  int4 hv = *(const int4*)&h8[tid * 4];
  int h = hv.x + hv.y + hv.z + hv.w;
  int ex0 = scan512_1(h, aux);
  dstart[tid] = ex0;
  __syncthreads();
  // 3 x 3-bit stable split rounds -> tile sorted by 9-bit digit
  int t0 = tid * 16;
  for (int rr = 0; rr < 3; ++rr) {
    int sh = shift + 3 * rr;
    unsigned long long key[16];
    unsigned long long cpack = 0;               // 8 x 8-bit digit counters
#pragma unroll
    for (int k = 0; k < 16; ++k) {
      key[k] = kk[phys16(t0 + k)];
      cpack += 1ULL << (((int)(key[k] >> sh) & 7) << 3);
    }
    int v4[4], ex[4], tot[4];
#pragma unroll
    for (int j = 0; j < 4; ++j) {
      unsigned pair = (unsigned)(cpack >> (16 * j));
      v4[j] = (int)((pair & 0xffu) | ((pair & 0xff00u) << 8));
    }
    scan512_x4(v4, ex, tot, aux);   // internal barriers also order reads-before-writes
    unsigned long long startq0, startq1;        // 8 start positions, 4x16-bit each
    {
      int a = 0, s8[8];
#pragma unroll
      for (int j = 0; j < 4; ++j) {
        int tlo = tot[j] & 0xffff, thi = tot[j] >> 16;
        int elo = ex[j] & 0xffff,  ehi = ex[j] >> 16;
        s8[2 * j]     = a + elo; a += tlo;
        s8[2 * j + 1] = a + ehi; a += thi;
      }
      startq0 = (unsigned long long)(unsigned)s8[0]
              | ((unsigned long long)(unsigned)s8[1] << 16)
              | ((unsigned long long)(unsigned)s8[2] << 32)
              | ((unsigned long long)(unsigned)s8[3] << 48);
      startq1 = (unsigned long long)(unsigned)s8[4]
              | ((unsigned long long)(unsigned)s8[5] << 16)
              | ((unsigned long long)(unsigned)s8[6] << 32)
              | ((unsigned long long)(unsigned)s8[7] << 48);
    }
#pragma unroll
    for (int k = 0; k < 16; ++k) {
      int d = (int)(key[k] >> sh) & 7;
      int fs = (d & 3) << 4;
      unsigned long long inc = 1ULL << fs;
      int pos;
      if (d < 4) { pos = (int)((startq0 >> fs) & 0xffffu); startq0 += inc; }
      else       { pos = (int)((startq1 >> fs) & 0xffffu); startq1 += inc; }
      kk[phys16(pos)] = key[k];
    }
    __syncthreads();
  }
  // direct-addressed scatter: read back in sorted order
#pragma unroll
  for (int r = 0; r < 16; ++r) {
    int i = tid + r * TH;
    unsigned long long k1 = kk[phys16(i)];
    int d = (int)((k1 >> shift) & (RADIX - 1));
    dst[(size_t)(gbase[d] + (i - dstart[d]))] = k1;
  }
}

// ---------------- unique count (coalesced, shfl-based) ----------------
// R2: counting is order-insensitive, so read COALESCED (ulonglong2, 1KB per
// wave instruction) and get the prev-element via __shfl_up + a register
// carry.  Wave w scans the contiguous span [w*1024, (w+1)*1024) of the tile.
// Replaces the old per-thread-16-consecutive pattern (64 cache lines per
// wave instruction -> ~16x L1/TA request amplification).
__global__ __launch_bounds__(TH) void k_uniq_count(const unsigned long long* __restrict__ A,
                                                   int* __restrict__ uPart,
                                                   const int* counters) {
  __shared__ int lds[8];
  int ac = activeChunks(counters);
  if ((int)blockIdx.x >= ac) { if (threadIdx.x == 0) uPart[blockIdx.x] = 0; return; }
  int tid = threadIdx.x;
  int lane = tid & 63, w = tid >> 6;           // 8 waves x 1024-element spans
  size_t wbase = (size_t)blockIdx.x * CHUNK + (size_t)w * 1024;
  unsigned long long carry = (wbase == 0) ? 0ULL : A[wbase - 1];
  int c = 0;
#pragma unroll
  for (int r = 0; r < 8; ++r) {
    ulonglong2 v = *(const ulonglong2*)&A[wbase + r * 128 + lane * 2];
    unsigned long long pl = __shfl_up(v.y, 1, 64);
    unsigned long long last = __shfl(v.y, 63, 64);
    unsigned long long p0 = (lane == 0) ? carry : pl;
    c += (v.x != SENTK && v.x != p0) ? 1 : 0;
    c += (v.y != SENTK && v.y != v.x) ? 1 : 0;
    carry = last;
  }
#pragma unroll
  for (int off = 32; off; off >>= 1) c += __shfl_down(c, off, 64);
  if (lane == 0) lds[w] = c;
  __syncthreads();
  if (tid == 0) {
    int s = 0;
#pragma unroll
    for (int q = 0; q < 8; ++q) s += lds[q];
    uPart[blockIdx.x] = s;
  }
}

// ---------------- final decoder write ----------------
// R2: coalesced global read -> LDS staging (phys16, the proven k_rscatter2
// pattern), per-thread-16 uniqueness+compaction from LDS, then the same
// 64KB LDS is REUSED for the sq/sr staging (all kk reads complete before
// scan512_1's internal barriers, so the overwrite is ordered).
__global__ __launch_bounds__(TH) void k_final(const unsigned long long* __restrict__ A,
                                              const int* __restrict__ uPart,
                                              const int* counters, float* __restrict__ out) {
  __shared__ unsigned long long kk[CHUNK];     // 64 KB; reused as sq/sr below
  __shared__ int aux[9];
  __shared__ int sscnt;
  int ac = activeChunks(counters);
  if ((int)blockIdx.x >= ac) return;
  int tid = threadIdx.x;
  size_t cb = (size_t)blockIdx.x * CHUNK;
  const ulonglong2* s2 = (const ulonglong2*)(A + cb);
#pragma unroll
  for (int r = 0; r < 8; ++r) {
    ulonglong2 v = s2[tid + r * TH];
    int i = 2 * (tid + r * TH);
    kk[phys16(i)] = v.x;
    kk[phys16(i + 1)] = v.y;
  }
  __syncthreads();
  int t0 = tid * 16;
  unsigned long long v[16];
  int f[16], c = 0;
  unsigned long long prev = (t0 == 0) ? ((cb == 0) ? 0ULL : A[cb - 1])
                                      : kk[phys16(t0 - 1)];
#pragma unroll
  for (int k = 0; k < 16; ++k) {
    v[k] = kk[phys16(t0 + k)];
    f[k] = (v[k] != SENTK && v[k] != prev) ? 1 : 0;
    c += f[k];
    prev = v[k];
  }
  int ex = scan512_1(c, aux);      // internal barriers: all kk reads done after
  if (tid == TH - 1) sscnt = ex + c;
  __syncthreads();
  float* sq = (float*)kk;          // reuse: 8192 + 8192 floats = 64 KB exactly
  float* sr = sq + CHUNK;
  int j = ex;
#pragma unroll
  for (int k = 0; k < 16; ++k) {
    if (f[k]) {
      sq[j] = (float)(unsigned)(v[k] >> 18);        // row (exact: < 2^24)
      sr[j] = (float)(unsigned)(v[k] & 262143u);    // col
      j++;
    }
  }
  __syncthreads();
  int cnt = sscnt;
  int jb = 1 + uPart[blockIdx.x];   // +1: slot 0 is the always-present hash 0
  for (int i = tid; i < cnt; i += TH) {
    out[OUT_DR + jb + i] = sq[i];
    out[OUT_DC + jb + i] = sr[i];
  }
}

// dec_vals fill (1.0 below totU, 0 after) + zero tails of dec_rows/cols + slot 0
__global__ __launch_bounds__(256) void k_dectail(const int* counters, float* out) {
  int i = (blockIdx.x * 256 + threadIdx.x) * 4;
  if (i >= MOUT) return;
  int totU = counters[3] + 1;
  float4 dv;
  dv.x = (i + 0 < totU) ? 1.0f : 0.0f;
  dv.y = (i + 1 < totU) ? 1.0f : 0.0f;
  dv.z = (i + 2 < totU) ? 1.0f : 0.0f;
  dv.w = (i + 3 < totU) ? 1.0f : 0.0f;
  *(float4*)&out[OUT_DV + i] = dv;
  if (i + 3 >= totU) {
    float4 z = make_float4(0.0f, 0.0f, 0.0f, 0.0f);
    if (i >= totU) {
      *(float4*)&out[OUT_DR + i] = z;
      *(float4*)&out[OUT_DC + i] = z;
    } else {
#pragma unroll
      for (int k = 0; k < 4; ++k)
        if (i + k >= totU) { out[OUT_DR + i + k] = 0.0f; out[OUT_DC + i + k] = 0.0f; }
    }
  }
  if (i == 0) { out[OUT_DR] = 0.0f; out[OUT_DC] = 0.0f; }
}

// ---------------- host launcher ----------------
extern "C" void kernel_launch(void* const* d_in, const int* in_sizes, int n_in,
                              void* d_out, int out_size, void* d_ws, size_t ws_size,
                              hipStream_t stream) {
  const int* rows = (const int*)d_in[1];   // d_in[0]=adj_vals (unused by reference outputs)
  const int* cols = (const int*)d_in[2];
  const int* seeds = (const int*)d_in[3];
  float* out = (float*)d_out;

  // workspace layout
  char* ws = (char*)d_ws;
  size_t off = 0;
  auto alloc = [&](size_t bytes) -> char* {
    char* p = ws + off;
    off += (bytes + 255) & ~(size_t)255;
    return p;
  };
  unsigned long long* A = (unsigned long long*)alloc(MP * 8);
  uint8_t* alive = (uint8_t*)alloc(EDGES);
  char* zbase = ws + off;                       // ---- zeroed zone ----
  uint8_t* frontier = (uint8_t*)alloc(NNODE);
  uint8_t* nextf = (uint8_t*)alloc(NNODE);
  uint8_t* masked = (uint8_t*)alloc(NNODE);
  int* deg8 = (int*)alloc((size_t)8 * NNODE16 * 4);
  int* counters = (int*)alloc(256 * 4);         // [1]=tem_num [2]=tailCnt [3]=uniqSum
  unsigned* tstate = (unsigned*)alloc((size_t)4 * 256 * 4);   // 4 passes x lookback state
  size_t zsize = (size_t)((ws + off) - zbase);  // ---- end zeroed zone ----
  float* dnorm = (float*)alloc((size_t)NNODE * 4);
  int* mlist = (int*)alloc((size_t)NNODE * 4);
  int* hist = (int*)alloc((size_t)NHIST * 4);
  int* uPart = (int*)alloc(2048 * 4);
  int* mPart = (int*)alloc(256 * 4);

  // radix ping-pong buffer B lives in the (later-overwritten) dec region of d_out
  unsigned long long* Bbuf = (unsigned long long*)(out + OUT_DR);

  // JAX key derivation (threefry_partitionable semantics)
  uint32_t ks0, ks1, kr0, kr1, kc0, kc1, s10, s11, s20, s21;
  tf2x32(0u, 42u, 0u, 0u, ks0, ks1);
  tf2x32(0u, 42u, 0u, 1u, kr0, kr1);
  tf2x32(0u, 42u, 0u, 2u, kc0, kc1);
  tf2x32(ks0, ks1, 0u, 0u, s10, s11);
  tf2x32(ks0, ks1, 0u, 1u, s20, s21);

  hipMemsetAsync(zbase, 0, zsize, stream);

  const int EB = EDGES / 256;                // 15625
  const int NB = (NNODE + 255) / 256;        // 586

  k_seed<<<2, 256, 0, stream>>>(seeds, frontier, masked);
  k_bfs0<<<VNB, 256, 0, stream>>>(rows, cols, frontier, alive, nextf, out);
  k_bfs1deg<<<VNB, 256, 0, stream>>>(rows, cols, nextf, alive, deg8);
  k_sample<<<(NSAMP + 255) / 256, 256, 0, stream>>>(masked, s10, s11, s20, s21);
  k_dnorm<<<NB, 256, 0, stream>>>(deg8, dnorm, masked, nextf);
  k_enctail<<<ENB, 256, 0, stream>>>(rows, cols, alive, dnorm, out, A, counters);

  // masked node list (ascending) + tem_num
  k_mreduce<<<MB, 256, 0, stream>>>(masked, mPart);
  k_scan_small<<<1, 1024, 0, stream>>>(mPart, MB, counters + 1);
  k_mscatter<<<MB, 256, 0, stream>>>(masked, mPart, mlist);

  // pairs + self loops at fixed slots; tail already appended compacted
  k_build_pairs<<<EB, 256, 0, stream>>>(mlist, counters, A, kr0, kr1, kc0, kc1);
  k_build_self<<<NB, 256, 0, stream>>>(A);
  k_pad<<<CHUNK / 256, 256, 0, stream>>>(A, counters);

  // radix sort: A -> B -> A -> B -> A (4 passes x 9 bits over active chunks)
  unsigned long long* src = A;
  unsigned long long* dst = Bbuf;
  const int shifts[4] = {0, 9, 18, 27};
  for (int p = 0; p < 4; ++p) {
    k_rhist2<<<NC, TH, 0, stream>>>(src, hist, shifts[p], counters);
    k_scan_lb<<<SNT, 256, 0, stream>>>(hist, tstate + (size_t)p * 256);
    k_rscatter2<<<NC, TH, 0, stream>>>(src, dst, hist, shifts[p], counters);
    unsigned long long* t = src; src = dst; dst = t;
  }
  // sorted result now in A (src == A)

  k_uniq_count<<<NTILE, TH, 0, stream>>>(src, uPart, counters);
  k_scan_small<<<1, 1024, 0, stream>>>(uPart, NTILE, counters + 3);
  k_final<<<NTILE, TH, 0, stream>>>(src, uPart, counters, out);
  k_dectail<<<(MOUT / 4 + 255) / 256, 256, 0, stream>>>(counters, out);
}

// Round 5
// 931.827 us; speedup vs baseline: 1.0667x; 1.0667x over previous
//
#include <hip/hip_runtime.h>
#include <stdint.h>

// ---------------- problem constants ----------------
#define NNODE   150000
#define NNODE16 150016             // 293 * 512 exactly; deg array size
#define EDGES   4000000
#define NSEED   500
#define NSAMP   15000              // int(150000 * 0.1)
#define MOUT    12150000           // 3E + N : decoder output length
#define SENTK   0xFFFFFFFFFFFFFFFFULL
#define SPAN    150000ULL
#define MULTK   51616ULL           // ((2^32 % 150000)^2) % 150000
#define FIXED   8150000            // pairs (8M) + self loops (150k) fixed slots

// hash encoding: h = (r << 18) | c.  Order-preserving bijection of the
// reference's r*150000+c (both lexicographic in (r,c), c < 150000 < 2^18),
// so the sorted-unique sequence is identical while decode is shift/mask.
// Max value = 149999<<18 | 149999 < 2^36 -> exactly 4 x 9-bit radix passes.

// sort geometry: 8192-key chunks, one tile per block.
// NOTE (R5 post-mortem): LSD radix REQUIRES a stable per-pass scatter — the
// in-LDS 3x3-bit split below is what preserves lower-digit order across
// passes. Do not replace with atomic-rank placement.
// NOTE (R1 post-mortem, this session): do NOT fuse unique+final via a
// 1488-block ticketed lookback — agent-scope atomic spin traffic starved the
// kernel to 770 GB/s / 172 µs. Lookback is only safe at all-resident grid
// sizes with short walks (k_scan_lb, 186 blocks).
// NOTE (R3/R4, this session): global atomics on gfx950 execute at the
// memory-side point REGARDLESS of scope hint or privatization layout
// (measured: identical 117us / 91MB WRITE for blockIdx&7-dev-scope vs
// XCD-id-wg-scope). Cost ~48B fabric write per op, ~17G ops/s service rate.
// The only fix is FEWER atomics -> block-aggregated bucketed counting below.
#define CHUNK   8192
#define TH      512
#define NC      1488               // max chunks; multiple of 8 for XCD swizzle
#define NCX     (NC / 8)           // 186
#define MP      ((size_t)NC * CHUNK)
#define RADIX   512
#define NHIST   (RADIX * NC)       // 761,856
#define SNT     (NHIST / 4096)     // 186 lookback-scan tiles (exact)
#define NTILE   NC                 // uniq/final tiles == chunks

// enctail geometry
#define EBLK    2048
#define ENB     ((EDGES + EBLK - 1) / EBLK)   // 1954

// vectorized edge-pass geometry (4 edges/thread)
#define VNB     ((EDGES + 1023) / 1024)       // 3907

// degree-count geometry (R4): 16 edges/thread, 512-thread blocks
#define DB_EDG  8192
#define DB_NB   ((EDGES + DB_EDG - 1) / DB_EDG)   // 489
#define NBUCK   293                // ceil(150000/512) node buckets
#define BCAP    16384              // per-bucket segment capacity (>20 sigma)

// masked-node compaction geometry
#define MTILE   2048
#define MB      ((NNODE + MTILE - 1) / MTILE)   // 74

// out layout (float32): [rows E][cols E][enc E][dec_rows M][dec_cols M][dec_vals M]
#define OUT_DR  12000000
#define OUT_DC  24150000
#define OUT_DV  36300000

// ---------------- threefry2x32 (JAX-exact, 20 rounds) ----------------
__host__ __device__ inline void tf2x32(uint32_t k0, uint32_t k1,
                                       uint32_t x0, uint32_t x1,
                                       uint32_t& o0, uint32_t& o1) {
  uint32_t ks2 = k0 ^ k1 ^ 0x1BD11BDAu;
  x0 += k0; x1 += k1;
#define TFR(d) { x0 += x1; x1 = (x1 << d) | (x1 >> (32 - d)); x1 ^= x0; }
  TFR(13) TFR(15) TFR(26) TFR(6)
  x0 += k1; x1 += ks2 + 1u;
  TFR(17) TFR(29) TFR(16) TFR(24)
  x0 += ks2; x1 += k0 + 2u;
  TFR(13) TFR(15) TFR(26) TFR(6)
  x0 += k0; x1 += k1 + 3u;
  TFR(17) TFR(29) TFR(16) TFR(24)
  x0 += k1; x1 += ks2 + 4u;
  TFR(13) TFR(15) TFR(26) TFR(6)
  x0 += ks2; x1 += k0 + 5u;
#undef TFR
  o0 = x0; o1 = x1;
}

__device__ inline unsigned long long tf_bits64(uint32_t k0, uint32_t k1, uint32_t i) {
  uint32_t o0, o1;
  tf2x32(k0, k1, 0u, i, o0, o1);
  return ((unsigned long long)o0 << 32) | o1;
}

// active chunk count (device, from tail append counter)
__device__ inline int activeChunks(const int* counters) {
  int m2 = FIXED + counters[2];
  return (m2 + CHUNK - 1) / CHUNK;
}

// ---------------- block primitives ----------------
__device__ inline int block_excl_scan_256(int v, int* lds /*>=5 ints*/, int& total) {
  int lane = threadIdx.x & 63, wid = threadIdx.x >> 6;
  int inc = v;
#pragma unroll
  for (int off = 1; off < 64; off <<= 1) {
    int y = __shfl_up(inc, off, 64);
    if (lane >= off) inc += y;
  }
  if (lane == 63) lds[wid] = inc;
  __syncthreads();
  if (threadIdx.x == 0) {
    int a = 0;
#pragma unroll
    for (int w = 0; w < 4; ++w) { int t = lds[w]; lds[w] = a; a += t; }
    lds[4] = a;
  }
  __syncthreads();
  total = lds[4];
  int res = inc - v + lds[wid];
  __syncthreads();
  return res;
}

// exclusive scan of 4 packed ints across 512 threads; aux >= 36 ints.
__device__ inline void scan512_x4(const int v[4], int ex[4], int tot[4], int* aux) {
  int lane = threadIdx.x & 63, wid = threadIdx.x >> 6;
  int inc[4];
#pragma unroll
  for (int j = 0; j < 4; ++j) inc[j] = v[j];
#pragma unroll
  for (int off = 1; off < 64; off <<= 1) {
#pragma unroll
    for (int j = 0; j < 4; ++j) {
      int y = __shfl_up(inc[j], off, 64);
      if (lane >= off) inc[j] += y;
    }
  }
  if (lane == 63) {
#pragma unroll
    for (int j = 0; j < 4; ++j) aux[j * 8 + wid] = inc[j];
  }
  __syncthreads();
  if (threadIdx.x == 0) {
#pragma unroll
    for (int j = 0; j < 4; ++j) {
      int a = 0;
#pragma unroll
      for (int w = 0; w < 8; ++w) { int t = aux[j * 8 + w]; aux[j * 8 + w] = a; a += t; }
      aux[32 + j] = a;
    }
  }
  __syncthreads();
#pragma unroll
  for (int j = 0; j < 4; ++j) {
    ex[j] = inc[j] - v[j] + aux[j * 8 + wid];
    tot[j] = aux[32 + j];
  }
}

__device__ inline int scan512_1(int v, int* aux /*>=9 ints*/) {
  int lane = threadIdx.x & 63, wid = threadIdx.x >> 6;
  int inc = v;
#pragma unroll
  for (int off = 1; off < 64; off <<= 1) {
    int y = __shfl_up(inc, off, 64);
    if (lane >= off) inc += y;
  }
  if (lane == 63) aux[wid] = inc;
  __syncthreads();
  if (threadIdx.x == 0) {
    int a = 0;
#pragma unroll
    for (int w = 0; w < 8; ++w) { int t = aux[w]; aux[w] = a; a += t; }
  }
  __syncthreads();
  return inc - v + aux[wid];
}

// wave-parallel decoupled-lookback: returns exclusive prefix for `tile` over
// packed state entries (bit31:30 = status {0 invalid,1 aggregate,2 prefix},
// bits 29:0 = value).  ONLY safe for all-resident grids (<=256 blocks) with
// short walks — see R1 post-mortem note above.
__device__ inline int lookback64(unsigned* state, int tile) {
  int lane = threadIdx.x;   // caller guarantees threadIdx.x < 64
  int acc = 0, cur = tile;
  for (;;) {
    int idx = cur - 1 - lane;
    unsigned v = 0;
    if (idx >= 0) {
      v = __hip_atomic_load(&state[idx], __ATOMIC_ACQUIRE, __HIP_MEMORY_SCOPE_AGENT);
      while ((v >> 30) == 0u)
        v = __hip_atomic_load(&state[idx], __ATOMIC_ACQUIRE, __HIP_MEMORY_SCOPE_AGENT);
    }
    unsigned st = (idx >= 0) ? (v >> 30) : 0u;
    int val = (int)(v & 0x3FFFFFFFu);
    unsigned long long pm = __ballot(st == 2u);
    int stop = pm ? (__ffsll((unsigned long long)pm) - 1) : 64;
    int contrib = (idx >= 0 && lane <= stop) ? val : 0;
#pragma unroll
    for (int off = 32; off; off >>= 1) contrib += __shfl_down(contrib, off, 64);
    acc += __shfl(contrib, 0, 64);           // broadcast so loop stays uniform
    if (stop < 64) break;
    cur -= 64;
  }
  return acc;
}

// LDS swizzle: rotate within 16-element rows to break 16-stride bank aliasing
__device__ inline int phys16(int p) { return (p & ~15) | ((p + (p >> 4)) & 15); }

// ---------------- BFS / enc kernels (fused) ----------------
__global__ __launch_bounds__(256) void k_seed(const int* seeds, uint8_t* frontier, uint8_t* masked) {
  int i = blockIdx.x * 256 + threadIdx.x;
  if (i < NSEED) { int v = seeds[i]; frontier[v] = 1; masked[v] = 1; }
}

// bfs hop 0 + rows/cols output copy; 4 edges/thread (MLP for the gathers).
// Writes alive[] fully (memset removed).
__global__ __launch_bounds__(256) void k_bfs0(const int* rows, const int* cols,
                                              const uint8_t* frontier, uint8_t* alive, uint8_t* nxt,
                                              float* out) {
  int g = blockIdx.x * 1024 + threadIdx.x * 4;
  if (g >= EDGES) return;
  if (g + 4 <= EDGES) {
    int4 r4 = *(const int4*)&rows[g];
    int4 c4 = *(const int4*)&cols[g];
    int rr[4] = {r4.x, r4.y, r4.z, r4.w};
    int cc[4] = {c4.x, c4.y, c4.z, c4.w};
    *(float4*)&out[g] = make_float4((float)rr[0], (float)rr[1], (float)rr[2], (float)rr[3]);
    *(float4*)&out[EDGES + g] = make_float4((float)cc[0], (float)cc[1], (float)cc[2], (float)cc[3]);
    uint8_t al[4];
#pragma unroll
    for (int k = 0; k < 4; ++k) {
      int hit = frontier[rr[k]] | frontier[cc[k]];
      al[k] = (uint8_t)(1 - hit);
      if (hit) { nxt[rr[k]] = 1; nxt[cc[k]] = 1; }
    }
    *(uchar4*)&alive[g] = make_uchar4(al[0], al[1], al[2], al[3]);
  } else {
    for (int e = g; e < EDGES; ++e) {
      int r = rows[e], c = cols[e];
      out[e] = (float)r;
      out[EDGES + e] = (float)c;
      int hit = frontier[r] | frontier[c];
      alive[e] = (uint8_t)(1 - hit);
      if (hit) { nxt[r] = 1; nxt[c] = 1; }
    }
  }
}

// bfs hop 1 + bucketed degree partition (R4).
// Finalizes alive[], then counts alive rows into a 293-bucket LDS histogram,
// reserves ONE global range per nonzero bucket (<=293 global atomics/block,
// 143K total vs 2M per-edge atomics = 18x fewer at the measured ~17G/s
// service rate), and scatters the 9-bit local node ids (u16) into per-bucket
// segments for k_degcount.
__global__ __launch_bounds__(512) void k_bfs1part(const int* rows, const int* cols,
                                                  const uint8_t* nxt, uint8_t* alive,
                                                  int* bucketCnt, uint16_t* seg) {
  __shared__ int cnt[NBUCK];
  __shared__ int cur[NBUCK];
  int tid = threadIdx.x;
  for (int i = tid; i < NBUCK; i += 512) cnt[i] = 0;
  __syncthreads();
  int base = blockIdx.x * DB_EDG;
  int rr[16];
  unsigned amask = 0;
#pragma unroll
  for (int g4 = 0; g4 < 4; ++g4) {
    int e0 = base + g4 * 2048 + tid * 4;
    if (e0 + 4 <= EDGES) {
      int4 r4 = *(const int4*)&rows[e0];
      int4 c4 = *(const int4*)&cols[e0];
      uchar4 a4 = *(const uchar4*)&alive[e0];
      int rl[4] = {r4.x, r4.y, r4.z, r4.w};
      int cl[4] = {c4.x, c4.y, c4.z, c4.w};
      uint8_t aa[4] = {a4.x, a4.y, a4.z, a4.w};
      uint8_t na[4];
#pragma unroll
      for (int k = 0; k < 4; ++k) {
        int a = aa[k];
        if (a && (nxt[rl[k]] | nxt[cl[k]])) a = 0;
        na[k] = (uint8_t)a;
        rr[g4 * 4 + k] = rl[k];
        if (a) { amask |= 1u << (g4 * 4 + k); atomicAdd(&cnt[rl[k] >> 9], 1); }
      }
      *(uchar4*)&alive[e0] = make_uchar4(na[0], na[1], na[2], na[3]);
    } else {
      for (int k = 0; k < 4; ++k) {
        int e = e0 + k;
        rr[g4 * 4 + k] = 0;
        if (e < EDGES) {
          int a = alive[e];
          int r = rows[e];
          if (a && (nxt[r] | nxt[cols[e]])) a = 0;
          alive[e] = (uint8_t)a;
          rr[g4 * 4 + k] = r;
          if (a) { amask |= 1u << (g4 * 4 + k); atomicAdd(&cnt[r >> 9], 1); }
        }
      }
    }
  }
  __syncthreads();
  // reserve global ranges: one global atomic per nonzero bucket
  for (int b = tid; b < NBUCK; b += 512) {
    int c = cnt[b];
    cur[b] = c ? atomicAdd(&bucketCnt[b], c) : 0;
  }
  __syncthreads();
  // scatter local 9-bit node ids (rank via LDS cursor)
  while (amask) {
    int k = __ffs(amask) - 1;
    amask &= amask - 1;
    int r = rr[k];
    int b = r >> 9;
    int pos = atomicAdd(&cur[b], 1);
    if (pos < BCAP) seg[(size_t)b * BCAP + pos] = (uint16_t)(r & 511);
  }
}

// per-bucket degree histogram: block b owns nodes [b*512, b*512+512).
// LDS atomics only; one coalesced non-atomic 512-int store. Zero global
// atomics. (293*512 = 150016 = NNODE16 exactly.)
__global__ __launch_bounds__(512) void k_degcount(const uint16_t* __restrict__ seg,
                                                  const int* __restrict__ bucketCnt,
                                                  int* __restrict__ deg) {
  __shared__ int h[512];
  int b = blockIdx.x;
  h[threadIdx.x] = 0;
  __syncthreads();
  int n = bucketCnt[b];
  if (n > BCAP) n = BCAP;
  const uint16_t* s = seg + (size_t)b * BCAP;
  for (int i = threadIdx.x; i < n; i += 512)
    atomicAdd(&h[s[i]], 1);
  __syncthreads();
  deg[b * 512 + threadIdx.x] = h[threadIdx.x];
}

__global__ __launch_bounds__(256) void k_sample(uint8_t* masked,
                                                uint32_t a0, uint32_t a1, uint32_t b0, uint32_t b1) {
  int i = blockIdx.x * 256 + threadIdx.x;
  if (i >= NSAMP) return;
  unsigned long long hi = tf_bits64(a0, a1, (uint32_t)i);
  unsigned long long lo = tf_bits64(b0, b1, (uint32_t)i);
  unsigned long long off = ((hi % SPAN) * MULTK + (lo % SPAN)) % SPAN;
  masked[off] = 1;
}

// dnorm + fused masked|=nxt (R1: folds the old k_masked_or launch; nxt is
// final after k_bfs0, masked not read until k_mreduce -> ordering safe)
__global__ __launch_bounds__(256) void k_dnorm(const int* deg, float* dnorm,
                                               uint8_t* masked, const uint8_t* nxt) {
  int v = blockIdx.x * 256 + threadIdx.x;
  if (v < NNODE) {
    float x = (float)deg[v] + 1e-12f;   // integer-valued count is exact in f32
    dnorm[v] = (float)(1.0 / sqrt((double)x));
    masked[v] |= nxt[v];
  }
}

// encoder values + compacted tail-hash append.
// 2048 edges/block -> 1954 block-level atomics (same-address atomic service
// rate ~12ns was R4's 187us bottleneck at 15625 atomics).
__global__ __launch_bounds__(256) void k_enctail(const int* rows, const int* cols,
                                                 const uint8_t* alive, const float* dnorm,
                                                 float* out, unsigned long long* A, int* counters) {
  __shared__ int lds[8];
  __shared__ unsigned long long stage[EBLK];
  __shared__ int sbase;
  int base = blockIdx.x * EBLK;
  unsigned long long vv[8];
  int emit[8], c = 0;
#pragma unroll
  for (int k = 0; k < 8; ++k) {
    int e = base + k * 256 + threadIdx.x;
    emit[k] = 0;
    if (e < EDGES) {
      int r = rows[e], cc = cols[e];
      int a = alive[e];
      out[2 * EDGES + e] = a ? dnorm[r] * dnorm[cc] : 0.0f;
      unsigned long long v = ((unsigned long long)(unsigned)r << 18) | (unsigned)cc;
      if (a && v) { emit[k] = 1; vv[k] = v; c++; }
    }
  }
  int total;
  int ex = block_excl_scan_256(c, lds, total);
#pragma unroll
  for (int k = 0; k < 8; ++k) {
    if (emit[k]) stage[ex++] = vv[k];
  }
  if (threadIdx.x == 0) sbase = total ? atomicAdd(&counters[2], total) : 0;
  __syncthreads();
  int sb = sbase;
  for (int i = threadIdx.x; i < total; i += 256)
    A[(size_t)FIXED + sb + i] = stage[i];
}

// ---------------- masked-node compaction ----------------
__global__ __launch_bounds__(256) void k_mreduce(const uint8_t* masked, int* mPart) {
  __shared__ int lds[4];
  int base = blockIdx.x * MTILE;
  int s = 0;
  for (int i = threadIdx.x; i < MTILE; i += 256) {
    int idx = base + i;
    if (idx < NNODE) s += masked[idx];
  }
#pragma unroll
  for (int off = 32; off; off >>= 1) s += __shfl_down(s, off, 64);
  if ((threadIdx.x & 63) == 0) lds[threadIdx.x >> 6] = s;
  __syncthreads();
  if (threadIdx.x == 0) mPart[blockIdx.x] = lds[0] + lds[1] + lds[2] + lds[3];
}

__global__ __launch_bounds__(1024) void k_scan_small(int* part, int m, int* totalOut) {
  __shared__ int a[2048];
  int tid = threadIdx.x;
  a[tid] = (tid < m) ? part[tid] : 0;
  a[tid + 1024] = (tid + 1024 < m) ? part[tid + 1024] : 0;
  __syncthreads();
  for (int off = 1; off < 2048; off <<= 1) {
    int v1 = 0, v2;
    if (tid >= off) v1 = a[tid - off];
    v2 = a[tid + 1024 - off];
    __syncthreads();
    if (tid >= off) a[tid] += v1;
    a[tid + 1024] += v2;
    __syncthreads();
  }
  if (tid < m) part[tid] = (tid == 0) ? 0 : a[tid - 1];
  if (tid + 1024 < m) part[tid + 1024] = a[tid + 1023];
  if (tid == 0 && totalOut) *totalOut = a[2047];
}

__global__ __launch_bounds__(256) void k_mscatter(const uint8_t* masked, const int* mPart, int* mlist) {
  __shared__ int lds[8];
  int t0 = blockIdx.x * MTILE + threadIdx.x * 8;
  int c = 0;
#pragma unroll
  for (int k = 0; k < 8; ++k) { int idx = t0 + k; c += (idx < NNODE) ? masked[idx] : 0; }
  int total;
  int ex = block_excl_scan_256(c, lds, total);
  int run = mPart[blockIdx.x] + ex;
#pragma unroll
  for (int k = 0; k < 8; ++k) {
    int idx = t0 + k;
    if (idx < NNODE && masked[idx]) mlist[run++] = idx;
  }
}

// ---------------- hash building ----------------
// dead / zero hashes are written as 0 (not SENTK): zeros sort to the front,
// are never counted as uniques (prev inits to 0; hash 0 is handled by the +1).
__global__ __launch_bounds__(256) void k_build_pairs(const int* mlist, const int* counters,
                                                     unsigned long long* A,
                                                     uint32_t r0, uint32_t r1, uint32_t c0, uint32_t c1) {
  int e = blockIdx.x * 256 + threadIdx.x;
  long long tem = counters[1];
  unsigned long long bits = tf_bits64(r0, r1, (uint32_t)e);
  double u1 = __longlong_as_double((long long)((bits >> 12) | 0x3FF0000000000000ULL)) - 1.0;
  long long i1 = (long long)(u1 * (double)tem); if (i1 > tem - 1) i1 = tem - 1;
  bits = tf_bits64(c0, c1, (uint32_t)e);
  double u2 = __longlong_as_double((long long)((bits >> 12) | 0x3FF0000000000000ULL)) - 1.0;
  long long i2 = (long long)(u2 * (double)tem); if (i2 > tem - 1) i2 = tem - 1;
  unsigned long long tr = (unsigned long long)mlist[i1];
  unsigned long long tc = (unsigned long long)mlist[i2];
  A[2 * (size_t)e]     = (tr << 18) | tc;
  A[2 * (size_t)e + 1] = (tc << 18) | tr;
}

__global__ __launch_bounds__(256) void k_build_self(unsigned long long* A) {
  int v = blockIdx.x * 256 + threadIdx.x;
  if (v >= NNODE) return;
  unsigned long long u = (unsigned long long)v;
  A[2 * (size_t)EDGES + v] = (u << 18) | u;     // v=0 -> 0, fine
}

// pad [m2, AC*CHUNK) with sentinels (< CHUNK elements)
__global__ __launch_bounds__(256) void k_pad(unsigned long long* A, const int* counters) {
  int m2 = FIXED + counters[2];
  int ac = (m2 + CHUNK - 1) / CHUNK;
  size_t idx = (size_t)m2 + blockIdx.x * 256 + threadIdx.x;
  if (idx < (size_t)ac * CHUNK) A[idx] = SENTK;
}

// ---------------- LSD radix sort: 4 passes x 9 bits, 8192-key chunks ----------------
__global__ __launch_bounds__(TH) void k_rhist2(const unsigned long long* __restrict__ src,
                                               int* __restrict__ hist, int shift,
                                               const int* counters) {
  __shared__ int h8[RADIX * 4];
  int tid = threadIdx.x;
  int ac = activeChunks(counters);
  if ((int)blockIdx.x >= ac) { hist[(size_t)tid * NC + blockIdx.x] = 0; return; }
  for (int i = tid; i < RADIX * 4; i += TH) h8[i] = 0;
  __syncthreads();
  const ulonglong2* s2 = (const ulonglong2*)(src + (size_t)blockIdx.x * CHUNK);
  int rep = tid & 3, scnt = 0;
#pragma unroll
  for (int r = 0; r < 8; ++r) {
    ulonglong2 v = s2[tid + r * TH];
    int d0 = (int)((v.x >> shift) & (RADIX - 1));
    int d1 = (int)((v.y >> shift) & (RADIX - 1));
    if (d0 == RADIX - 1) scnt++; else atomicAdd(&h8[d0 * 4 + rep], 1);
    if (d1 == RADIX - 1) scnt++; else atomicAdd(&h8[d1 * 4 + rep], 1);
  }
  if (scnt) atomicAdd(&h8[(RADIX - 1) * 4 + rep], scnt);
  __syncthreads();
  int4 hv = *(const int4*)&h8[tid * 4];
  hist[(size_t)tid * NC + blockIdx.x] = hv.x + hv.y + hv.z + hv.w;
}

// single-kernel exclusive scan of hist (NHIST = 186 x 4096 ints) via
// decoupled lookback.  186 blocks of 256 threads are ALL resident on 256
// CUs simultaneously, so blockIdx-order spin-waits cannot deadlock and the
// walk terminates within <=3 rounds.  Replaces the 3-kernel
// reduce/small/apply chain (2 launches + 1 whole-GPU single-block bubble
// per radix pass).
__global__ __launch_bounds__(256) void k_scan_lb(int* __restrict__ g,
                                                 unsigned* __restrict__ tstate) {
  __shared__ int lds[8];
  __shared__ int sbase;
  int tile = blockIdx.x;
  int base = tile * 4096 + threadIdx.x * 16;
  int x[16];
  {
    int4 q0 = *(const int4*)&g[base];
    int4 q1 = *(const int4*)&g[base + 4];
    int4 q2 = *(const int4*)&g[base + 8];
    int4 q3 = *(const int4*)&g[base + 12];
    x[0]=q0.x; x[1]=q0.y; x[2]=q0.z;  x[3]=q0.w;
    x[4]=q1.x; x[5]=q1.y; x[6]=q1.z;  x[7]=q1.w;
    x[8]=q2.x; x[9]=q2.y; x[10]=q2.z; x[11]=q2.w;
    x[12]=q3.x; x[13]=q3.y; x[14]=q3.z; x[15]=q3.w;
  }
  int s = 0;
#pragma unroll
  for (int k = 0; k < 16; ++k) { int t = x[k]; x[k] = s; s += t; }
  int total;
  int ex = block_excl_scan_256(s, lds, total);
  if (threadIdx.x == 0) {
    unsigned st = (tile == 0) ? 0x80000000u : 0x40000000u;
    __hip_atomic_store(&tstate[tile], st | (unsigned)total,
                       __ATOMIC_RELEASE, __HIP_MEMORY_SCOPE_AGENT);
    if (tile == 0) sbase = 0;
  }
  if (tile > 0 && threadIdx.x < 64) {
    int acc = lookback64(tstate, tile);
    if (threadIdx.x == 0) {
      sbase = acc;
      __hip_atomic_store(&tstate[tile], 0x80000000u | (unsigned)(acc + total),
                         __ATOMIC_RELEASE, __HIP_MEMORY_SCOPE_AGENT);
    }
  }
  __syncthreads();
  int bb = sbase + ex;
#pragma unroll
  for (int k = 0; k < 16; ++k) x[k] += bb;
  *(int4*)&g[base]      = make_int4(x[0], x[1], x[2], x[3]);
  *(int4*)&g[base + 4]  = make_int4(x[4], x[5], x[6], x[7]);
  *(int4*)&g[base + 8]  = make_int4(x[8], x[9], x[10], x[11]);
  *(int4*)&g[base + 12] = make_int4(x[12], x[13], x[14], x[15]);
}

// STABLE scatter (required for LSD): 3x3-bit in-LDS split rounds sort the
// tile by the 9-bit digit while preserving intra-digit (= prior-pass) order,
// then a direct-addressed coalesced write per digit segment.
// R7: packed bit-field ranking. R8: keys held in a single u64 LDS array
// (halves the ds_read/ds_write instruction count vs the klo/khi split;
// phys16 on 8B elements spreads stride-16 walks over 16 bank-pairs = floor).
__global__ __launch_bounds__(TH) void k_rscatter2(const unsigned long long* __restrict__ src,
                                                  unsigned long long* __restrict__ dst,
                                                  const int* __restrict__ hist, int shift,
                                                  const int* counters) {
  __shared__ unsigned long long kk[CHUNK];
  __shared__ int h8[RADIX * 4];
  __shared__ int dstart[RADIX], gbase[RADIX];
  __shared__ int aux[40];
  int tid = threadIdx.x;
  // XCD-contiguous chunk swizzle: adjacent chunks on the same XCD, temporally adjacent
  int chunk = (blockIdx.x & 7) * NCX + (blockIdx.x >> 3);
  int ac = activeChunks(counters);
  if (chunk >= ac) return;
  size_t cbase = (size_t)chunk * CHUNK;
  gbase[tid] = hist[(size_t)tid * NC + chunk];
  for (int i = tid; i < RADIX * 4; i += TH) h8[i] = 0;
  __syncthreads();
  int rep = tid & 3;
  const ulonglong2* s2 = (const ulonglong2*)(src + cbase);
  int scnt = 0;
#pragma unroll
  for (int r = 0; r < 8; ++r) {
    ulonglong2 v = s2[tid + r * TH];
    int i = 2 * (tid + r * TH);
    kk[phys16(i)] = v.x;
    kk[phys16(i + 1)] = v.y;
    int d0 = (int)((v.x >> shift) & (RADIX - 1));
    int d1 = (int)((v.y >> shift) & (RADIX - 1));
    if (d0 == RADIX - 1) scnt++; else atomicAdd(&h8[d0 * 4 + rep], 1);
    if (d1 == RADIX - 1) scnt++; else atomicAdd(&h8[d1 * 4 + rep], 1);
  }
  if (scnt) atomicAdd(&h8[(RADIX - 1) * 4 + rep], scnt);
  __syncthreads();
  int4 hv = *(const int4*)&h8[tid * 4];
  int h = hv.x + hv.y + hv.z + hv.w;
  int ex0 = scan512_1(h, aux);
  dstart[tid] = ex0;
  __syncthreads();
  // 3 x 3-bit stable split rounds -> tile sorted by 9-bit digit
  int t0 = tid * 16;
  for (int rr = 0; rr < 3; ++rr) {
    int sh = shift + 3 * rr;
    unsigned long long key[16];
    unsigned long long cpack = 0;               // 8 x 8-bit digit counters
#pragma unroll
    for (int k = 0; k < 16; ++k) {
      key[k] = kk[phys16(t0 + k)];
      cpack += 1ULL << (((int)(key[k] >> sh) & 7) << 3);
    }
    int v4[4], ex[4], tot[4];
#pragma unroll
    for (int j = 0; j < 4; ++j) {
      unsigned pair = (unsigned)(cpack >> (16 * j));
      v4[j] = (int)((pair & 0xffu) | ((pair & 0xff00u) << 8));
    }
    scan512_x4(v4, ex, tot, aux);   // internal barriers also order reads-before-writes
    unsigned long long startq0, startq1;        // 8 start positions, 4x16-bit each
    {
      int a = 0, s8[8];
#pragma unroll
      for (int j = 0; j < 4; ++j) {
        int tlo = tot[j] & 0xffff, thi = tot[j] >> 16;
        int elo = ex[j] & 0xffff,  ehi = ex[j] >> 16;
        s8[2 * j]     = a + elo; a += tlo;
        s8[2 * j + 1] = a + ehi; a += thi;
      }
      startq0 = (unsigned long long)(unsigned)s8[0]
              | ((unsigned long long)(unsigned)s8[1] << 16)
              | ((unsigned long long)(unsigned)s8[2] << 32)
              | ((unsigned long long)(unsigned)s8[3] << 48);
      startq1 = (unsigned long long)(unsigned)s8[4]
              | ((unsigned long long)(unsigned)s8[5] << 16)
              | ((unsigned long long)(unsigned)s8[6] << 32)
              | ((unsigned long long)(unsigned)s8[7] << 48);
    }
#pragma unroll
    for (int k = 0; k < 16; ++k) {
      int d = (int)(key[k] >> sh) & 7;
      int fs = (d & 3) << 4;
      unsigned long long inc = 1ULL << fs;
      int pos;
      if (d < 4) { pos = (int)((startq0 >> fs) & 0xffffu); startq0 += inc; }
      else       { pos = (int)((startq1 >> fs) & 0xffffu); startq1 += inc; }
      kk[phys16(pos)] = key[k];
    }
    __syncthreads();
  }
  // direct-addressed scatter: read back in sorted order
#pragma unroll
  for (int r = 0; r < 16; ++r) {
    int i = tid + r * TH;
    unsigned long long k1 = kk[phys16(i)];
    int d = (int)((k1 >> shift) & (RADIX - 1));
    dst[(size_t)(gbase[d] + (i - dstart[d]))] = k1;
  }
}

// ---------------- unique count (coalesced, shfl-based) ----------------
// R2: counting is order-insensitive, so read COALESCED (ulonglong2, 1KB per
// wave instruction) and get the prev-element via __shfl_up + a register
// carry.  Wave w scans the contiguous span [w*1024, (w+1)*1024) of the tile.
__global__ __launch_bounds__(TH) void k_uniq_count(const unsigned long long* __restrict__ A,
                                                   int* __restrict__ uPart,
                                                   const int* counters) {
  __shared__ int lds[8];
  int ac = activeChunks(counters);
  if ((int)blockIdx.x >= ac) { if (threadIdx.x == 0) uPart[blockIdx.x] = 0; return; }
  int tid = threadIdx.x;
  int lane = tid & 63, w = tid >> 6;           // 8 waves x 1024-element spans
  size_t wbase = (size_t)blockIdx.x * CHUNK + (size_t)w * 1024;
  unsigned long long carry = (wbase == 0) ? 0ULL : A[wbase - 1];
  int c = 0;
#pragma unroll
  for (int r = 0; r < 8; ++r) {
    ulonglong2 v = *(const ulonglong2*)&A[wbase + r * 128 + lane * 2];
    unsigned long long pl = __shfl_up(v.y, 1, 64);
    unsigned long long last = __shfl(v.y, 63, 64);
    unsigned long long p0 = (lane == 0) ? carry : pl;
    c += (v.x != SENTK && v.x != p0) ? 1 : 0;
    c += (v.y != SENTK && v.y != v.x) ? 1 : 0;
    carry = last;
  }
#pragma unroll
  for (int off = 32; off; off >>= 1) c += __shfl_down(c, off, 64);
  if (lane == 0) lds[w] = c;
  __syncthreads();
  if (tid == 0) {
    int s = 0;
#pragma unroll
    for (int q = 0; q < 8; ++q) s += lds[q];
    uPart[blockIdx.x] = s;
  }
}

// ---------------- final decoder write ----------------
// R2: coalesced global read -> LDS staging (phys16, the proven k_rscatter2
// pattern), per-thread-16 uniqueness+compaction from LDS, then the same
// 64KB LDS is REUSED for the sq/sr staging (all kk reads complete before
// scan512_1's internal barriers, so the overwrite is ordered).
__global__ __launch_bounds__(TH) void k_final(const unsigned long long* __restrict__ A,
                                              const int* __restrict__ uPart,
                                              const int* counters, float* __restrict__ out) {
  __shared__ unsigned long long kk[CHUNK];     // 64 KB; reused as sq/sr below
  __shared__ int aux[9];
  __shared__ int sscnt;
  int ac = activeChunks(counters);
  if ((int)blockIdx.x >= ac) return;
  int tid = threadIdx.x;
  size_t cb = (size_t)blockIdx.x * CHUNK;
  const ulonglong2* s2 = (const ulonglong2*)(A + cb);
#pragma unroll
  for (int r = 0; r < 8; ++r) {
    ulonglong2 v = s2[tid + r * TH];
    int i = 2 * (tid + r * TH);
    kk[phys16(i)] = v.x;
    kk[phys16(i + 1)] = v.y;
  }
  __syncthreads();
  int t0 = tid * 16;
  unsigned long long v[16];
  int f[16], c = 0;
  unsigned long long prev = (t0 == 0) ? ((cb == 0) ? 0ULL : A[cb - 1])
                                      : kk[phys16(t0 - 1)];
#pragma unroll
  for (int k = 0; k < 16; ++k) {
    v[k] = kk[phys16(t0 + k)];
    f[k] = (v[k] != SENTK && v[k] != prev) ? 1 : 0;
    c += f[k];
    prev = v[k];
  }
  int ex = scan512_1(c, aux);      // internal barriers: all kk reads done after
  if (tid == TH - 1) sscnt = ex + c;
  __syncthreads();
  float* sq = (float*)kk;          // reuse: 8192 + 8192 floats = 64 KB exactly
  float* sr = sq + CHUNK;
  int j = ex;
#pragma unroll
  for (int k = 0; k < 16; ++k) {
    if (f[k]) {
      sq[j] = (float)(unsigned)(v[k] >> 18);        // row (exact: < 2^24)
      sr[j] = (float)(unsigned)(v[k] & 262143u);    // col
      j++;
    }
  }
  __syncthreads();
  int cnt = sscnt;
  int jb = 1 + uPart[blockIdx.x];   // +1: slot 0 is the always-present hash 0
  for (int i = tid; i < cnt; i += TH) {
    out[OUT_DR + jb + i] = sq[i];
    out[OUT_DC + jb + i] = sr[i];
  }
}

// dec_vals fill (1.0 below totU, 0 after) + zero tails of dec_rows/cols + slot 0
__global__ __launch_bounds__(256) void k_dectail(const int* counters, float* out) {
  int i = (blockIdx.x * 256 + threadIdx.x) * 4;
  if (i >= MOUT) return;
  int totU = counters[3] + 1;
  float4 dv;
  dv.x = (i + 0 < totU) ? 1.0f : 0.0f;
  dv.y = (i + 1 < totU) ? 1.0f : 0.0f;
  dv.z = (i + 2 < totU) ? 1.0f : 0.0f;
  dv.w = (i + 3 < totU) ? 1.0f : 0.0f;
  *(float4*)&out[OUT_DV + i] = dv;
  if (i + 3 >= totU) {
    float4 z = make_float4(0.0f, 0.0f, 0.0f, 0.0f);
    if (i >= totU) {
      *(float4*)&out[OUT_DR + i] = z;
      *(float4*)&out[OUT_DC + i] = z;
    } else {
#pragma unroll
      for (int k = 0; k < 4; ++k)
        if (i + k >= totU) { out[OUT_DR + i + k] = 0.0f; out[OUT_DC + i + k] = 0.0f; }
    }
  }
  if (i == 0) { out[OUT_DR] = 0.0f; out[OUT_DC] = 0.0f; }
}

// ---------------- host launcher ----------------
extern "C" void kernel_launch(void* const* d_in, const int* in_sizes, int n_in,
                              void* d_out, int out_size, void* d_ws, size_t ws_size,
                              hipStream_t stream) {
  const int* rows = (const int*)d_in[1];   // d_in[0]=adj_vals (unused by reference outputs)
  const int* cols = (const int*)d_in[2];
  const int* seeds = (const int*)d_in[3];
  float* out = (float*)d_out;

  // workspace layout
  char* ws = (char*)d_ws;
  size_t off = 0;
  auto alloc = [&](size_t bytes) -> char* {
    char* p = ws + off;
    off += (bytes + 255) & ~(size_t)255;
    return p;
  };
  unsigned long long* A = (unsigned long long*)alloc(MP * 8);
  uint8_t* alive = (uint8_t*)alloc(EDGES);
  uint16_t* seg = (uint16_t*)alloc((size_t)NBUCK * BCAP * 2);   // 9.6 MB
  int* deg = (int*)alloc((size_t)NNODE16 * 4);                  // fully written
  char* zbase = ws + off;                       // ---- zeroed zone ----
  uint8_t* frontier = (uint8_t*)alloc(NNODE);
  uint8_t* nextf = (uint8_t*)alloc(NNODE);
  uint8_t* masked = (uint8_t*)alloc(NNODE);
  int* bucketCnt = (int*)alloc(NBUCK * 4);
  int* counters = (int*)alloc(256 * 4);         // [1]=tem_num [2]=tailCnt [3]=uniqSum
  unsigned* tstate = (unsigned*)alloc((size_t)4 * 256 * 4);   // 4 passes x lookback state
  size_t zsize = (size_t)((ws + off) - zbase);  // ---- end zeroed zone ----
  float* dnorm = (float*)alloc((size_t)NNODE * 4);
  int* mlist = (int*)alloc((size_t)NNODE * 4);
  int* hist = (int*)alloc((size_t)NHIST * 4);
  int* uPart = (int*)alloc(2048 * 4);
  int* mPart = (int*)alloc(256 * 4);

  // radix ping-pong buffer B lives in the (later-overwritten) dec region of d_out
  unsigned long long* Bbuf = (unsigned long long*)(out + OUT_DR);

  // JAX key derivation (threefry_partitionable semantics)
  uint32_t ks0, ks1, kr0, kr1, kc0, kc1, s10, s11, s20, s21;
  tf2x32(0u, 42u, 0u, 0u, ks0, ks1);
  tf2x32(0u, 42u, 0u, 1u, kr0, kr1);
  tf2x32(0u, 42u, 0u, 2u, kc0, kc1);
  tf2x32(ks0, ks1, 0u, 0u, s10, s11);
  tf2x32(ks0, ks1, 0u, 1u, s20, s21);

  hipMemsetAsync(zbase, 0, zsize, stream);

  const int EB = EDGES / 256;                // 15625
  const int NB = (NNODE + 255) / 256;        // 586

  k_seed<<<2, 256, 0, stream>>>(seeds, frontier, masked);
  k_bfs0<<<VNB, 256, 0, stream>>>(rows, cols, frontier, alive, nextf, out);
  k_bfs1part<<<DB_NB, 512, 0, stream>>>(rows, cols, nextf, alive, bucketCnt, seg);
  k_degcount<<<NBUCK, 512, 0, stream>>>(seg, bucketCnt, deg);
  k_sample<<<(NSAMP + 255) / 256, 256, 0, stream>>>(masked, s10, s11, s20, s21);
  k_dnorm<<<NB, 256, 0, stream>>>(deg, dnorm, masked, nextf);
  k_enctail<<<ENB, 256, 0, stream>>>(rows, cols, alive, dnorm, out, A, counters);

  // masked node list (ascending) + tem_num
  k_mreduce<<<MB, 256, 0, stream>>>(masked, mPart);
  k_scan_small<<<1, 1024, 0, stream>>>(mPart, MB, counters + 1);
  k_mscatter<<<MB, 256, 0, stream>>>(masked, mPart, mlist);

  // pairs + self loops at fixed slots; tail already appended compacted
  k_build_pairs<<<EB, 256, 0, stream>>>(mlist, counters, A, kr0, kr1, kc0, kc1);
  k_build_self<<<NB, 256, 0, stream>>>(A);
  k_pad<<<CHUNK / 256, 256, 0, stream>>>(A, counters);

  // radix sort: A -> B -> A -> B -> A (4 passes x 9 bits over active chunks)
  unsigned long long* src = A;
  unsigned long long* dst = Bbuf;
  const int shifts[4] = {0, 9, 18, 27};
  for (int p = 0; p < 4; ++p) {
    k_rhist2<<<NC, TH, 0, stream>>>(src, hist, shifts[p], counters);
    k_scan_lb<<<SNT, 256, 0, stream>>>(hist, tstate + (size_t)p * 256);
    k_rscatter2<<<NC, TH, 0, stream>>>(src, dst, hist, shifts[p], counters);
    unsigned long long* t = src; src = dst; dst = t;
  }
  // sorted result now in A (src == A)

  k_uniq_count<<<NTILE, TH, 0, stream>>>(src, uPart, counters);
  k_scan_small<<<1, 1024, 0, stream>>>(uPart, NTILE, counters + 3);
  k_final<<<NTILE, TH, 0, stream>>>(src, uPart, counters, out);
  k_dectail<<<(MOUT / 4 + 255) / 256, 256, 0, stream>>>(counters, out);
}

// Round 6
// 917.721 us; speedup vs baseline: 1.0831x; 1.0154x over previous
//
#include <hip/hip_runtime.h>
#include <stdint.h>

// ---------------- problem constants ----------------
#define NNODE   150000
#define NNODE16 150016             // 293 * 512 exactly
#define EDGES   4000000
#define NSEED   500
#define NSAMP   15000              // int(150000 * 0.1)
#define MOUT    12150000           // 3E + N : decoder output length
#define SENTK   0xFFFFFFFFFFFFFFFFULL
#define SPAN    150000ULL
#define MULTK   51616ULL           // ((2^32 % 150000)^2) % 150000
#define FIXED   8150000            // pairs (8M) + self loops (150k) fixed slots

// hash encoding: h = (r << 18) | c.  Order-preserving bijection of the
// reference's r*150000+c (both lexicographic in (r,c), c < 150000 < 2^18),
// so the sorted-unique sequence is identical while decode is shift/mask.
// Max value = 149999<<18 | 149999 < 2^36 -> exactly 4 x 9-bit radix passes.

// sort geometry: 8192-key chunks, one tile per block.
// NOTE (R5 post-mortem): LSD radix REQUIRES a stable per-pass scatter — the
// in-LDS 3x3-bit split below is what preserves lower-digit order across
// passes. Do not replace with atomic-rank placement.
// NOTE (R1 post-mortem, this session): do NOT fuse unique+final via a
// 1488-block ticketed lookback — agent-scope atomic spin traffic starved the
// kernel to 770 GB/s / 172 µs. Lookback is only safe at all-resident grid
// sizes with short walks (k_scan_lb 186 blocks, k_mlist 74 blocks).
// NOTE (R3/R4, this session): global atomics on gfx950 execute at the
// memory-side point REGARDLESS of scope hint or privatization layout
// (measured: identical 117us / 91MB WRITE for blockIdx&7-dev-scope vs
// XCD-id-wg-scope). Cost ~48B fabric write per op, ~17G ops/s service rate.
// The only fix is FEWER atomics -> block-aggregated bucketed counting.
// NOTE (R5, this session): top-5 rocprof slots are now the harness's 775MB
// workspace re-poison fills (117us each) — our largest own dispatch is
// <116us and invisible; steer by dur_us deltas only.
#define CHUNK   8192
#define TH      512
#define NC      1488               // max chunks; multiple of 8 for XCD swizzle
#define NCX     (NC / 8)           // 186
#define MP      ((size_t)NC * CHUNK)
#define RADIX   512
#define NHIST   (RADIX * NC)       // 761,856
#define SNT     (NHIST / 4096)     // 186 lookback-scan tiles (exact)
#define NTILE   NC                 // uniq/final tiles == chunks

// enctail geometry
#define EBLK    2048
#define ENB     ((EDGES + EBLK - 1) / EBLK)   // 1954

// vectorized edge-pass geometry (4 edges/thread)
#define VNB     ((EDGES + 1023) / 1024)       // 3907

// degree-count geometry (R4): 16 edges/thread, 512-thread blocks
#define DB_EDG  8192
#define DB_NB   ((EDGES + DB_EDG - 1) / DB_EDG)   // 489
#define NBUCK   293                // ceil(150000/512) node buckets
#define BCAP    16384              // per-bucket segment capacity (>20 sigma)

// masked-node compaction geometry (R5: single 74-block lookback kernel)
#define MTILE   2048
#define MB      ((NNODE + MTILE - 1) / MTILE)   // 74

// out layout (float32): [rows E][cols E][enc E][dec_rows M][dec_cols M][dec_vals M]
#define OUT_DR  12000000
#define OUT_DC  24150000
#define OUT_DV  36300000

// ---------------- threefry2x32 (JAX-exact, 20 rounds) ----------------
__host__ __device__ inline void tf2x32(uint32_t k0, uint32_t k1,
                                       uint32_t x0, uint32_t x1,
                                       uint32_t& o0, uint32_t& o1) {
  uint32_t ks2 = k0 ^ k1 ^ 0x1BD11BDAu;
  x0 += k0; x1 += k1;
#define TFR(d) { x0 += x1; x1 = (x1 << d) | (x1 >> (32 - d)); x1 ^= x0; }
  TFR(13) TFR(15) TFR(26) TFR(6)
  x0 += k1; x1 += ks2 + 1u;
  TFR(17) TFR(29) TFR(16) TFR(24)
  x0 += ks2; x1 += k0 + 2u;
  TFR(13) TFR(15) TFR(26) TFR(6)
  x0 += k0; x1 += k1 + 3u;
  TFR(17) TFR(29) TFR(16) TFR(24)
  x0 += k1; x1 += ks2 + 4u;
  TFR(13) TFR(15) TFR(26) TFR(6)
  x0 += ks2; x1 += k0 + 5u;
#undef TFR
  o0 = x0; o1 = x1;
}

__device__ inline unsigned long long tf_bits64(uint32_t k0, uint32_t k1, uint32_t i) {
  uint32_t o0, o1;
  tf2x32(k0, k1, 0u, i, o0, o1);
  return ((unsigned long long)o0 << 32) | o1;
}

// active chunk count (device, from tail append counter)
__device__ inline int activeChunks(const int* counters) {
  int m2 = FIXED + counters[2];
  return (m2 + CHUNK - 1) / CHUNK;
}

// ---------------- block primitives ----------------
__device__ inline int block_excl_scan_256(int v, int* lds /*>=5 ints*/, int& total) {
  int lane = threadIdx.x & 63, wid = threadIdx.x >> 6;
  int inc = v;
#pragma unroll
  for (int off = 1; off < 64; off <<= 1) {
    int y = __shfl_up(inc, off, 64);
    if (lane >= off) inc += y;
  }
  if (lane == 63) lds[wid] = inc;
  __syncthreads();
  if (threadIdx.x == 0) {
    int a = 0;
#pragma unroll
    for (int w = 0; w < 4; ++w) { int t = lds[w]; lds[w] = a; a += t; }
    lds[4] = a;
  }
  __syncthreads();
  total = lds[4];
  int res = inc - v + lds[wid];
  __syncthreads();
  return res;
}

// exclusive scan of 4 packed ints across 512 threads; aux >= 36 ints.
__device__ inline void scan512_x4(const int v[4], int ex[4], int tot[4], int* aux) {
  int lane = threadIdx.x & 63, wid = threadIdx.x >> 6;
  int inc[4];
#pragma unroll
  for (int j = 0; j < 4; ++j) inc[j] = v[j];
#pragma unroll
  for (int off = 1; off < 64; off <<= 1) {
#pragma unroll
    for (int j = 0; j < 4; ++j) {
      int y = __shfl_up(inc[j], off, 64);
      if (lane >= off) inc[j] += y;
    }
  }
  if (lane == 63) {
#pragma unroll
    for (int j = 0; j < 4; ++j) aux[j * 8 + wid] = inc[j];
  }
  __syncthreads();
  if (threadIdx.x == 0) {
#pragma unroll
    for (int j = 0; j < 4; ++j) {
      int a = 0;
#pragma unroll
      for (int w = 0; w < 8; ++w) { int t = aux[j * 8 + w]; aux[j * 8 + w] = a; a += t; }
      aux[32 + j] = a;
    }
  }
  __syncthreads();
#pragma unroll
  for (int j = 0; j < 4; ++j) {
    ex[j] = inc[j] - v[j] + aux[j * 8 + wid];
    tot[j] = aux[32 + j];
  }
}

__device__ inline int scan512_1(int v, int* aux /*>=9 ints*/) {
  int lane = threadIdx.x & 63, wid = threadIdx.x >> 6;
  int inc = v;
#pragma unroll
  for (int off = 1; off < 64; off <<= 1) {
    int y = __shfl_up(inc, off, 64);
    if (lane >= off) inc += y;
  }
  if (lane == 63) aux[wid] = inc;
  __syncthreads();
  if (threadIdx.x == 0) {
    int a = 0;
#pragma unroll
    for (int w = 0; w < 8; ++w) { int t = aux[w]; aux[w] = a; a += t; }
  }
  __syncthreads();
  return inc - v + aux[wid];
}

// wave-parallel decoupled-lookback: returns exclusive prefix for `tile` over
// packed state entries (bit31:30 = status {0 invalid,1 aggregate,2 prefix},
// bits 29:0 = value).  ONLY safe for all-resident grids (<=256 blocks) with
// short walks — see R1 post-mortem note above.
__device__ inline int lookback64(unsigned* state, int tile) {
  int lane = threadIdx.x;   // caller guarantees threadIdx.x < 64
  int acc = 0, cur = tile;
  for (;;) {
    int idx = cur - 1 - lane;
    unsigned v = 0;
    if (idx >= 0) {
      v = __hip_atomic_load(&state[idx], __ATOMIC_ACQUIRE, __HIP_MEMORY_SCOPE_AGENT);
      while ((v >> 30) == 0u)
        v = __hip_atomic_load(&state[idx], __ATOMIC_ACQUIRE, __HIP_MEMORY_SCOPE_AGENT);
    }
    unsigned st = (idx >= 0) ? (v >> 30) : 0u;
    int val = (int)(v & 0x3FFFFFFFu);
    unsigned long long pm = __ballot(st == 2u);
    int stop = pm ? (__ffsll((unsigned long long)pm) - 1) : 64;
    int contrib = (idx >= 0 && lane <= stop) ? val : 0;
#pragma unroll
    for (int off = 32; off; off >>= 1) contrib += __shfl_down(contrib, off, 64);
    acc += __shfl(contrib, 0, 64);           // broadcast so loop stays uniform
    if (stop < 64) break;
    cur -= 64;
  }
  return acc;
}

// LDS swizzle: rotate within 16-element rows to break 16-stride bank aliasing
__device__ inline int phys16(int p) { return (p & ~15) | ((p + (p >> 4)) & 15); }

// ---------------- BFS / enc kernels (fused) ----------------
// R5: seed + sample fused — both only STORE 1s into frontier/masked (byte
// stores, no RMW -> no race even if concurrent; both precede any reader).
__global__ __launch_bounds__(256) void k_seedsample(const int* seeds, uint8_t* frontier,
                                                    uint8_t* masked,
                                                    uint32_t a0, uint32_t a1,
                                                    uint32_t b0, uint32_t b1) {
  int i = blockIdx.x * 256 + threadIdx.x;
  if (i < NSEED) { int v = seeds[i]; frontier[v] = 1; masked[v] = 1; }
  if (i < NSAMP) {
    unsigned long long hi = tf_bits64(a0, a1, (uint32_t)i);
    unsigned long long lo = tf_bits64(b0, b1, (uint32_t)i);
    unsigned long long off = ((hi % SPAN) * MULTK + (lo % SPAN)) % SPAN;
    masked[off] = 1;
  }
}

// bfs hop 0 + rows/cols output copy; 4 edges/thread (MLP for the gathers).
// Writes alive[] fully (memset removed).
__global__ __launch_bounds__(256) void k_bfs0(const int* rows, const int* cols,
                                              const uint8_t* frontier, uint8_t* alive, uint8_t* nxt,
                                              float* out) {
  int g = blockIdx.x * 1024 + threadIdx.x * 4;
  if (g >= EDGES) return;
  if (g + 4 <= EDGES) {
    int4 r4 = *(const int4*)&rows[g];
    int4 c4 = *(const int4*)&cols[g];
    int rr[4] = {r4.x, r4.y, r4.z, r4.w};
    int cc[4] = {c4.x, c4.y, c4.z, c4.w};
    *(float4*)&out[g] = make_float4((float)rr[0], (float)rr[1], (float)rr[2], (float)rr[3]);
    *(float4*)&out[EDGES + g] = make_float4((float)cc[0], (float)cc[1], (float)cc[2], (float)cc[3]);
    uint8_t al[4];
#pragma unroll
    for (int k = 0; k < 4; ++k) {
      int hit = frontier[rr[k]] | frontier[cc[k]];
      al[k] = (uint8_t)(1 - hit);
      if (hit) { nxt[rr[k]] = 1; nxt[cc[k]] = 1; }
    }
    *(uchar4*)&alive[g] = make_uchar4(al[0], al[1], al[2], al[3]);
  } else {
    for (int e = g; e < EDGES; ++e) {
      int r = rows[e], c = cols[e];
      out[e] = (float)r;
      out[EDGES + e] = (float)c;
      int hit = frontier[r] | frontier[c];
      alive[e] = (uint8_t)(1 - hit);
      if (hit) { nxt[r] = 1; nxt[c] = 1; }
    }
  }
}

// bfs hop 1 + bucketed degree partition (R4).
// Finalizes alive[], then counts alive rows into a 293-bucket LDS histogram,
// reserves ONE global range per nonzero bucket (<=293 global atomics/block,
// 143K total vs 2M per-edge atomics = 18x fewer at the measured ~17G/s
// service rate), and scatters the 9-bit local node ids (u16) into per-bucket
// segments for k_degnorm.
__global__ __launch_bounds__(512) void k_bfs1part(const int* rows, const int* cols,
                                                  const uint8_t* nxt, uint8_t* alive,
                                                  int* bucketCnt, uint16_t* seg) {
  __shared__ int cnt[NBUCK];
  __shared__ int cur[NBUCK];
  int tid = threadIdx.x;
  for (int i = tid; i < NBUCK; i += 512) cnt[i] = 0;
  __syncthreads();
  int base = blockIdx.x * DB_EDG;
  int rr[16];
  unsigned amask = 0;
#pragma unroll
  for (int g4 = 0; g4 < 4; ++g4) {
    int e0 = base + g4 * 2048 + tid * 4;
    if (e0 + 4 <= EDGES) {
      int4 r4 = *(const int4*)&rows[e0];
      int4 c4 = *(const int4*)&cols[e0];
      uchar4 a4 = *(const uchar4*)&alive[e0];
      int rl[4] = {r4.x, r4.y, r4.z, r4.w};
      int cl[4] = {c4.x, c4.y, c4.z, c4.w};
      uint8_t aa[4] = {a4.x, a4.y, a4.z, a4.w};
      uint8_t na[4];
#pragma unroll
      for (int k = 0; k < 4; ++k) {
        int a = aa[k];
        if (a && (nxt[rl[k]] | nxt[cl[k]])) a = 0;
        na[k] = (uint8_t)a;
        rr[g4 * 4 + k] = rl[k];
        if (a) { amask |= 1u << (g4 * 4 + k); atomicAdd(&cnt[rl[k] >> 9], 1); }
      }
      *(uchar4*)&alive[e0] = make_uchar4(na[0], na[1], na[2], na[3]);
    } else {
      for (int k = 0; k < 4; ++k) {
        int e = e0 + k;
        rr[g4 * 4 + k] = 0;
        if (e < EDGES) {
          int a = alive[e];
          int r = rows[e];
          if (a && (nxt[r] | nxt[cols[e]])) a = 0;
          alive[e] = (uint8_t)a;
          rr[g4 * 4 + k] = r;
          if (a) { amask |= 1u << (g4 * 4 + k); atomicAdd(&cnt[r >> 9], 1); }
        }
      }
    }
  }
  __syncthreads();
  // reserve global ranges: one global atomic per nonzero bucket
  for (int b = tid; b < NBUCK; b += 512) {
    int c = cnt[b];
    cur[b] = c ? atomicAdd(&bucketCnt[b], c) : 0;
  }
  __syncthreads();
  // scatter local 9-bit node ids (rank via LDS cursor)
  while (amask) {
    int k = __ffs(amask) - 1;
    amask &= amask - 1;
    int r = rr[k];
    int b = r >> 9;
    int pos = atomicAdd(&cur[b], 1);
    if (pos < BCAP) seg[(size_t)b * BCAP + pos] = (uint16_t)(r & 511);
  }
}

// R5: degcount + dnorm + masked|=nxt fused.  Block b owns nodes
// [b*512, b*512+512): LDS histogram over its segment (LDS atomics only),
// then dnorm/masked computed directly from the LDS counts — the deg array
// and its global round-trip are eliminated.  Zero global atomics.
__global__ __launch_bounds__(512) void k_degnorm(const uint16_t* __restrict__ seg,
                                                 const int* __restrict__ bucketCnt,
                                                 float* __restrict__ dnorm,
                                                 uint8_t* masked, const uint8_t* nxt) {
  __shared__ int h[512];
  int b = blockIdx.x;
  h[threadIdx.x] = 0;
  __syncthreads();
  int n = bucketCnt[b];
  if (n > BCAP) n = BCAP;
  const uint16_t* s = seg + (size_t)b * BCAP;
  for (int i = threadIdx.x; i < n; i += 512)
    atomicAdd(&h[s[i]], 1);
  __syncthreads();
  int v = b * 512 + threadIdx.x;
  if (v < NNODE) {
    float x = (float)h[threadIdx.x] + 1e-12f;   // integer count exact in f32
    dnorm[v] = (float)(1.0 / sqrt((double)x));
    masked[v] |= nxt[v];
  }
}

// encoder values + compacted tail-hash append.
// 2048 edges/block -> 1954 block-level atomics (same-address atomic service
// rate ~12ns was R4's 187us bottleneck at 15625 atomics).
__global__ __launch_bounds__(256) void k_enctail(const int* rows, const int* cols,
                                                 const uint8_t* alive, const float* dnorm,
                                                 float* out, unsigned long long* A, int* counters) {
  __shared__ int lds[8];
  __shared__ unsigned long long stage[EBLK];
  __shared__ int sbase;
  int base = blockIdx.x * EBLK;
  unsigned long long vv[8];
  int emit[8], c = 0;
#pragma unroll
  for (int k = 0; k < 8; ++k) {
    int e = base + k * 256 + threadIdx.x;
    emit[k] = 0;
    if (e < EDGES) {
      int r = rows[e], cc = cols[e];
      int a = alive[e];
      out[2 * EDGES + e] = a ? dnorm[r] * dnorm[cc] : 0.0f;
      unsigned long long v = ((unsigned long long)(unsigned)r << 18) | (unsigned)cc;
      if (a && v) { emit[k] = 1; vv[k] = v; c++; }
    }
  }
  int total;
  int ex = block_excl_scan_256(c, lds, total);
#pragma unroll
  for (int k = 0; k < 8; ++k) {
    if (emit[k]) stage[ex++] = vv[k];
  }
  if (threadIdx.x == 0) sbase = total ? atomicAdd(&counters[2], total) : 0;
  __syncthreads();
  int sb = sbase;
  for (int i = threadIdx.x; i < total; i += 256)
    A[(size_t)FIXED + sb + i] = stage[i];
}

// ---------------- masked-node compaction (R5: single lookback kernel) -----
// Replaces mreduce + scan_small + mscatter.  74 blocks — all-resident
// (74 < 256 CUs), so the blockIdx-ordered lookback cannot deadlock and the
// walk is <=2 rounds.  Last tile publishes counters[1] = tem_num.
__global__ __launch_bounds__(256) void k_mlist(const uint8_t* __restrict__ masked,
                                               int* __restrict__ mlist,
                                               unsigned* __restrict__ mstate,
                                               int* __restrict__ counters) {
  __shared__ int lds[8];
  __shared__ int sbase;
  int tile = blockIdx.x;
  int t0 = tile * MTILE + threadIdx.x * 8;
  uint8_t m[8];
  int c = 0;
#pragma unroll
  for (int k = 0; k < 8; ++k) {
    int idx = t0 + k;
    m[k] = (idx < NNODE) ? masked[idx] : (uint8_t)0;
    c += m[k];
  }
  int total;
  int ex = block_excl_scan_256(c, lds, total);
  if (threadIdx.x == 0) {
    unsigned st = (tile == 0) ? 0x80000000u : 0x40000000u;
    __hip_atomic_store(&mstate[tile], st | (unsigned)total,
                       __ATOMIC_RELEASE, __HIP_MEMORY_SCOPE_AGENT);
    if (tile == 0) sbase = 0;
  }
  if (tile > 0 && threadIdx.x < 64) {
    int acc = lookback64(mstate, tile);
    if (threadIdx.x == 0) {
      sbase = acc;
      __hip_atomic_store(&mstate[tile], 0x80000000u | (unsigned)(acc + total),
                         __ATOMIC_RELEASE, __HIP_MEMORY_SCOPE_AGENT);
    }
  }
  __syncthreads();
  int run = sbase + ex;
#pragma unroll
  for (int k = 0; k < 8; ++k) {
    int idx = t0 + k;
    if (idx < NNODE && m[k]) mlist[run++] = idx;
  }
  if (tile == MB - 1 && threadIdx.x == 0) counters[1] = sbase + total;
}

// ---------------- hash building ----------------
// dead / zero hashes are written as 0 (not SENTK): zeros sort to the front,
// are never counted as uniques (prev inits to 0; hash 0 is handled by the +1).
__global__ __launch_bounds__(256) void k_build_pairs(const int* mlist, const int* counters,
                                                     unsigned long long* A,
                                                     uint32_t r0, uint32_t r1, uint32_t c0, uint32_t c1) {
  int e = blockIdx.x * 256 + threadIdx.x;
  long long tem = counters[1];
  unsigned long long bits = tf_bits64(r0, r1, (uint32_t)e);
  double u1 = __longlong_as_double((long long)((bits >> 12) | 0x3FF0000000000000ULL)) - 1.0;
  long long i1 = (long long)(u1 * (double)tem); if (i1 > tem - 1) i1 = tem - 1;
  bits = tf_bits64(c0, c1, (uint32_t)e);
  double u2 = __longlong_as_double((long long)((bits >> 12) | 0x3FF0000000000000ULL)) - 1.0;
  long long i2 = (long long)(u2 * (double)tem); if (i2 > tem - 1) i2 = tem - 1;
  unsigned long long tr = (unsigned long long)mlist[i1];
  unsigned long long tc = (unsigned long long)mlist[i2];
  A[2 * (size_t)e]     = (tr << 18) | tc;
  A[2 * (size_t)e + 1] = (tc << 18) | tr;
}

// R5: self loops + sentinel pad fused (regions [2E, FIXED) and
// [m2, ac*CHUNK) are disjoint since FIXED = 2E + N exactly).
__global__ __launch_bounds__(256) void k_selfpad(unsigned long long* A, const int* counters) {
  int v = blockIdx.x * 256 + threadIdx.x;
  if (v < NNODE) {
    unsigned long long u = (unsigned long long)v;
    A[2 * (size_t)EDGES + v] = (u << 18) | u;   // v=0 -> 0, fine
  }
  int m2 = FIXED + counters[2];
  int ac = (m2 + CHUNK - 1) / CHUNK;
  int pad = ac * CHUNK - m2;                    // < CHUNK <= grid size
  if (v < pad) A[(size_t)m2 + v] = SENTK;
}

// ---------------- LSD radix sort: 4 passes x 9 bits, 8192-key chunks ----------------
__global__ __launch_bounds__(TH) void k_rhist2(const unsigned long long* __restrict__ src,
                                               int* __restrict__ hist, int shift,
                                               const int* counters) {
  __shared__ int h8[RADIX * 4];
  int tid = threadIdx.x;
  int ac = activeChunks(counters);
  if ((int)blockIdx.x >= ac) { hist[(size_t)tid * NC + blockIdx.x] = 0; return; }
  for (int i = tid; i < RADIX * 4; i += TH) h8[i] = 0;
  __syncthreads();
  const ulonglong2* s2 = (const ulonglong2*)(src + (size_t)blockIdx.x * CHUNK);
  int rep = tid & 3, scnt = 0;
#pragma unroll
  for (int r = 0; r < 8; ++r) {
    ulonglong2 v = s2[tid + r * TH];
    int d0 = (int)((v.x >> shift) & (RADIX - 1));
    int d1 = (int)((v.y >> shift) & (RADIX - 1));
    if (d0 == RADIX - 1) scnt++; else atomicAdd(&h8[d0 * 4 + rep], 1);
    if (d1 == RADIX - 1) scnt++; else atomicAdd(&h8[d1 * 4 + rep], 1);
  }
  if (scnt) atomicAdd(&h8[(RADIX - 1) * 4 + rep], scnt);
  __syncthreads();
  int4 hv = *(const int4*)&h8[tid * 4];
  hist[(size_t)tid * NC + blockIdx.x] = hv.x + hv.y + hv.z + hv.w;
}

// single-kernel exclusive scan of hist (NHIST = 186 x 4096 ints) via
// decoupled lookback.  186 blocks of 256 threads are ALL resident on 256
// CUs simultaneously, so blockIdx-order spin-waits cannot deadlock and the
// walk terminates within <=3 rounds.
__global__ __launch_bounds__(256) void k_scan_lb(int* __restrict__ g,
                                                 unsigned* __restrict__ tstate) {
  __shared__ int lds[8];
  __shared__ int sbase;
  int tile = blockIdx.x;
  int base = tile * 4096 + threadIdx.x * 16;
  int x[16];
  {
    int4 q0 = *(const int4*)&g[base];
    int4 q1 = *(const int4*)&g[base + 4];
    int4 q2 = *(const int4*)&g[base + 8];
    int4 q3 = *(const int4*)&g[base + 12];
    x[0]=q0.x; x[1]=q0.y; x[2]=q0.z;  x[3]=q0.w;
    x[4]=q1.x; x[5]=q1.y; x[6]=q1.z;  x[7]=q1.w;
    x[8]=q2.x; x[9]=q2.y; x[10]=q2.z; x[11]=q2.w;
    x[12]=q3.x; x[13]=q3.y; x[14]=q3.z; x[15]=q3.w;
  }
  int s = 0;
#pragma unroll
  for (int k = 0; k < 16; ++k) { int t = x[k]; x[k] = s; s += t; }
  int total;
  int ex = block_excl_scan_256(s, lds, total);
  if (threadIdx.x == 0) {
    unsigned st = (tile == 0) ? 0x80000000u : 0x40000000u;
    __hip_atomic_store(&tstate[tile], st | (unsigned)total,
                       __ATOMIC_RELEASE, __HIP_MEMORY_SCOPE_AGENT);
    if (tile == 0) sbase = 0;
  }
  if (tile > 0 && threadIdx.x < 64) {
    int acc = lookback64(tstate, tile);
    if (threadIdx.x == 0) {
      sbase = acc;
      __hip_atomic_store(&tstate[tile], 0x80000000u | (unsigned)(acc + total),
                         __ATOMIC_RELEASE, __HIP_MEMORY_SCOPE_AGENT);
    }
  }
  __syncthreads();
  int bb = sbase + ex;
#pragma unroll
  for (int k = 0; k < 16; ++k) x[k] += bb;
  *(int4*)&g[base]      = make_int4(x[0], x[1], x[2], x[3]);
  *(int4*)&g[base + 4]  = make_int4(x[4], x[5], x[6], x[7]);
  *(int4*)&g[base + 8]  = make_int4(x[8], x[9], x[10], x[11]);
  *(int4*)&g[base + 12] = make_int4(x[12], x[13], x[14], x[15]);
}

// STABLE scatter (required for LSD): 3x3-bit in-LDS split rounds sort the
// tile by the 9-bit digit while preserving intra-digit (= prior-pass) order,
// then a direct-addressed coalesced write per digit segment.
// R7: packed bit-field ranking. R8: keys held in a single u64 LDS array
// (halves the ds_read/ds_write instruction count vs the klo/khi split;
// phys16 on 8B elements spreads stride-16 walks over 16 bank-pairs = floor).
__global__ __launch_bounds__(TH) void k_rscatter2(const unsigned long long* __restrict__ src,
                                                  unsigned long long* __restrict__ dst,
                                                  const int* __restrict__ hist, int shift,
                                                  const int* counters) {
  __shared__ unsigned long long kk[CHUNK];
  __shared__ int h8[RADIX * 4];
  __shared__ int dstart[RADIX], gbase[RADIX];
  __shared__ int aux[40];
  int tid = threadIdx.x;
  // XCD-contiguous chunk swizzle: adjacent chunks on the same XCD, temporally adjacent
  int chunk = (blockIdx.x & 7) * NCX + (blockIdx.x >> 3);
  int ac = activeChunks(counters);
  if (chunk >= ac) return;
  size_t cbase = (size_t)chunk * CHUNK;
  gbase[tid] = hist[(size_t)tid * NC + chunk];
  for (int i = tid; i < RADIX * 4; i += TH) h8[i] = 0;
  __syncthreads();
  int rep = tid & 3;
  const ulonglong2* s2 = (const ulonglong2*)(src + cbase);
  int scnt = 0;
#pragma unroll
  for (int r = 0; r < 8; ++r) {
    ulonglong2 v = s2[tid + r * TH];
    int i = 2 * (tid + r * TH);
    kk[phys16(i)] = v.x;
    kk[phys16(i + 1)] = v.y;
    int d0 = (int)((v.x >> shift) & (RADIX - 1));
    int d1 = (int)((v.y >> shift) & (RADIX - 1));
    if (d0 == RADIX - 1) scnt++; else atomicAdd(&h8[d0 * 4 + rep], 1);
    if (d1 == RADIX - 1) scnt++; else atomicAdd(&h8[d1 * 4 + rep], 1);
  }
  if (scnt) atomicAdd(&h8[(RADIX - 1) * 4 + rep], scnt);
  __syncthreads();
  int4 hv = *(const int4*)&h8[tid * 4];
  int h = hv.x + hv.y + hv.z + hv.w;
  int ex0 = scan512_1(h, aux);
  dstart[tid] = ex0;
  __syncthreads();
  // 3 x 3-bit stable split rounds -> tile sorted by 9-bit digit
  int t0 = tid * 16;
  for (int rr = 0; rr < 3; ++rr) {
    int sh = shift + 3 * rr;
    unsigned long long key[16];
    unsigned long long cpack = 0;               // 8 x 8-bit digit counters
#pragma unroll
    for (int k = 0; k < 16; ++k) {
      key[k] = kk[phys16(t0 + k)];
      cpack += 1ULL << (((int)(key[k] >> sh) & 7) << 3);
    }
    int v4[4], ex[4], tot[4];
#pragma unroll
    for (int j = 0; j < 4; ++j) {
      unsigned pair = (unsigned)(cpack >> (16 * j));
      v4[j] = (int)((pair & 0xffu) | ((pair & 0xff00u) << 8));
    }
    scan512_x4(v4, ex, tot, aux);   // internal barriers also order reads-before-writes
    unsigned long long startq0, startq1;        // 8 start positions, 4x16-bit each
    {
      int a = 0, s8[8];
#pragma unroll
      for (int j = 0; j < 4; ++j) {
        int tlo = tot[j] & 0xffff, thi = tot[j] >> 16;
        int elo = ex[j] & 0xffff,  ehi = ex[j] >> 16;
        s8[2 * j]     = a + elo; a += tlo;
        s8[2 * j + 1] = a + ehi; a += thi;
      }
      startq0 = (unsigned long long)(unsigned)s8[0]
              | ((unsigned long long)(unsigned)s8[1] << 16)
              | ((unsigned long long)(unsigned)s8[2] << 32)
              | ((unsigned long long)(unsigned)s8[3] << 48);
      startq1 = (unsigned long long)(unsigned)s8[4]
              | ((unsigned long long)(unsigned)s8[5] << 16)
              | ((unsigned long long)(unsigned)s8[6] << 32)
              | ((unsigned long long)(unsigned)s8[7] << 48);
    }
#pragma unroll
    for (int k = 0; k < 16; ++k) {
      int d = (int)(key[k] >> sh) & 7;
      int fs = (d & 3) << 4;
      unsigned long long inc = 1ULL << fs;
      int pos;
      if (d < 4) { pos = (int)((startq0 >> fs) & 0xffffu); startq0 += inc; }
      else       { pos = (int)((startq1 >> fs) & 0xffffu); startq1 += inc; }
      kk[phys16(pos)] = key[k];
    }
    __syncthreads();
  }
  // direct-addressed scatter: read back in sorted order
#pragma unroll
  for (int r = 0; r < 16; ++r) {
    int i = tid + r * TH;
    unsigned long long k1 = kk[phys16(i)];
    int d = (int)((k1 >> shift) & (RADIX - 1));
    dst[(size_t)(gbase[d] + (i - dstart[d]))] = k1;
  }
}

// ---------------- unique count (coalesced, shfl-based) ----------------
// R2: counting is order-insensitive, so read COALESCED (ulonglong2, 1KB per
// wave instruction) and get the prev-element via __shfl_up + a register
// carry.  Wave w scans the contiguous span [w*1024, (w+1)*1024) of the tile.
__global__ __launch_bounds__(TH) void k_uniq_count(const unsigned long long* __restrict__ A,
                                                   int* __restrict__ uPart,
                                                   const int* counters) {
  __shared__ int lds[8];
  int ac = activeChunks(counters);
  if ((int)blockIdx.x >= ac) { if (threadIdx.x == 0) uPart[blockIdx.x] = 0; return; }
  int tid = threadIdx.x;
  int lane = tid & 63, w = tid >> 6;           // 8 waves x 1024-element spans
  size_t wbase = (size_t)blockIdx.x * CHUNK + (size_t)w * 1024;
  unsigned long long carry = (wbase == 0) ? 0ULL : A[wbase - 1];
  int c = 0;
#pragma unroll
  for (int r = 0; r < 8; ++r) {
    ulonglong2 v = *(const ulonglong2*)&A[wbase + r * 128 + lane * 2];
    unsigned long long pl = __shfl_up(v.y, 1, 64);
    unsigned long long last = __shfl(v.y, 63, 64);
    unsigned long long p0 = (lane == 0) ? carry : pl;
    c += (v.x != SENTK && v.x != p0) ? 1 : 0;
    c += (v.y != SENTK && v.y != v.x) ? 1 : 0;
    carry = last;
  }
#pragma unroll
  for (int off = 32; off; off >>= 1) c += __shfl_down(c, off, 64);
  if (lane == 0) lds[w] = c;
  __syncthreads();
  if (tid == 0) {
    int s = 0;
#pragma unroll
    for (int q = 0; q < 8; ++q) s += lds[q];
    uPart[blockIdx.x] = s;
  }
}

__global__ __launch_bounds__(1024) void k_scan_small(int* part, int m, int* totalOut) {
  __shared__ int a[2048];
  int tid = threadIdx.x;
  a[tid] = (tid < m) ? part[tid] : 0;
  a[tid + 1024] = (tid + 1024 < m) ? part[tid + 1024] : 0;
  __syncthreads();
  for (int off = 1; off < 2048; off <<= 1) {
    int v1 = 0, v2;
    if (tid >= off) v1 = a[tid - off];
    v2 = a[tid + 1024 - off];
    __syncthreads();
    if (tid >= off) a[tid] += v1;
    a[tid + 1024] += v2;
    __syncthreads();
  }
  if (tid < m) part[tid] = (tid == 0) ? 0 : a[tid - 1];
  if (tid + 1024 < m) part[tid + 1024] = a[tid + 1023];
  if (tid == 0 && totalOut) *totalOut = a[2047];
}

// ---------------- final decoder write ----------------
// R2: coalesced global read -> LDS staging (phys16, the proven k_rscatter2
// pattern), per-thread-16 uniqueness+compaction from LDS, then the same
// 64KB LDS is REUSED for the sq/sr staging (all kk reads complete before
// scan512_1's internal barriers, so the overwrite is ordered).
__global__ __launch_bounds__(TH) void k_final(const unsigned long long* __restrict__ A,
                                              const int* __restrict__ uPart,
                                              const int* counters, float* __restrict__ out) {
  __shared__ unsigned long long kk[CHUNK];     // 64 KB; reused as sq/sr below
  __shared__ int aux[9];
  __shared__ int sscnt;
  int ac = activeChunks(counters);
  if ((int)blockIdx.x >= ac) return;
  int tid = threadIdx.x;
  size_t cb = (size_t)blockIdx.x * CHUNK;
  const ulonglong2* s2 = (const ulonglong2*)(A + cb);
#pragma unroll
  for (int r = 0; r < 8; ++r) {
    ulonglong2 v = s2[tid + r * TH];
    int i = 2 * (tid + r * TH);
    kk[phys16(i)] = v.x;
    kk[phys16(i + 1)] = v.y;
  }
  __syncthreads();
  int t0 = tid * 16;
  unsigned long long v[16];
  int f[16], c = 0;
  unsigned long long prev = (t0 == 0) ? ((cb == 0) ? 0ULL : A[cb - 1])
                                      : kk[phys16(t0 - 1)];
#pragma unroll
  for (int k = 0; k < 16; ++k) {
    v[k] = kk[phys16(t0 + k)];
    f[k] = (v[k] != SENTK && v[k] != prev) ? 1 : 0;
    c += f[k];
    prev = v[k];
  }
  int ex = scan512_1(c, aux);      // internal barriers: all kk reads done after
  if (tid == TH - 1) sscnt = ex + c;
  __syncthreads();
  float* sq = (float*)kk;          // reuse: 8192 + 8192 floats = 64 KB exactly
  float* sr = sq + CHUNK;
  int j = ex;
#pragma unroll
  for (int k = 0; k < 16; ++k) {
    if (f[k]) {
      sq[j] = (float)(unsigned)(v[k] >> 18);        // row (exact: < 2^24)
      sr[j] = (float)(unsigned)(v[k] & 262143u);    // col
      j++;
    }
  }
  __syncthreads();
  int cnt = sscnt;
  int jb = 1 + uPart[blockIdx.x];   // +1: slot 0 is the always-present hash 0
  for (int i = tid; i < cnt; i += TH) {
    out[OUT_DR + jb + i] = sq[i];
    out[OUT_DC + jb + i] = sr[i];
  }
}

// dec_vals fill (1.0 below totU, 0 after) + zero tails of dec_rows/cols + slot 0
__global__ __launch_bounds__(256) void k_dectail(const int* counters, float* out) {
  int i = (blockIdx.x * 256 + threadIdx.x) * 4;
  if (i >= MOUT) return;
  int totU = counters[3] + 1;
  float4 dv;
  dv.x = (i + 0 < totU) ? 1.0f : 0.0f;
  dv.y = (i + 1 < totU) ? 1.0f : 0.0f;
  dv.z = (i + 2 < totU) ? 1.0f : 0.0f;
  dv.w = (i + 3 < totU) ? 1.0f : 0.0f;
  *(float4*)&out[OUT_DV + i] = dv;
  if (i + 3 >= totU) {
    float4 z = make_float4(0.0f, 0.0f, 0.0f, 0.0f);
    if (i >= totU) {
      *(float4*)&out[OUT_DR + i] = z;
      *(float4*)&out[OUT_DC + i] = z;
    } else {
#pragma unroll
      for (int k = 0; k < 4; ++k)
        if (i + k >= totU) { out[OUT_DR + i + k] = 0.0f; out[OUT_DC + i + k] = 0.0f; }
    }
  }
  if (i == 0) { out[OUT_DR] = 0.0f; out[OUT_DC] = 0.0f; }
}

// ---------------- host launcher ----------------
extern "C" void kernel_launch(void* const* d_in, const int* in_sizes, int n_in,
                              void* d_out, int out_size, void* d_ws, size_t ws_size,
                              hipStream_t stream) {
  const int* rows = (const int*)d_in[1];   // d_in[0]=adj_vals (unused by reference outputs)
  const int* cols = (const int*)d_in[2];
  const int* seeds = (const int*)d_in[3];
  float* out = (float*)d_out;

  // workspace layout
  char* ws = (char*)d_ws;
  size_t off = 0;
  auto alloc = [&](size_t bytes) -> char* {
    char* p = ws + off;
    off += (bytes + 255) & ~(size_t)255;
    return p;
  };
  unsigned long long* A = (unsigned long long*)alloc(MP * 8);
  uint8_t* alive = (uint8_t*)alloc(EDGES);
  uint16_t* seg = (uint16_t*)alloc((size_t)NBUCK * BCAP * 2);   // 9.6 MB
  char* zbase = ws + off;                       // ---- zeroed zone ----
  uint8_t* frontier = (uint8_t*)alloc(NNODE);
  uint8_t* nextf = (uint8_t*)alloc(NNODE);
  uint8_t* masked = (uint8_t*)alloc(NNODE);
  int* bucketCnt = (int*)alloc(NBUCK * 4);
  int* counters = (int*)alloc(256 * 4);         // [1]=tem_num [2]=tailCnt [3]=uniqSum
  unsigned* tstate = (unsigned*)alloc((size_t)4 * 256 * 4);   // 4 passes x lookback state
  unsigned* mstate = (unsigned*)alloc(256 * 4);               // k_mlist lookback state
  size_t zsize = (size_t)((ws + off) - zbase);  // ---- end zeroed zone ----
  float* dnorm = (float*)alloc((size_t)NNODE * 4);
  int* mlist = (int*)alloc((size_t)NNODE * 4);
  int* hist = (int*)alloc((size_t)NHIST * 4);
  int* uPart = (int*)alloc(2048 * 4);

  // radix ping-pong buffer B lives in the (later-overwritten) dec region of d_out
  unsigned long long* Bbuf = (unsigned long long*)(out + OUT_DR);

  // JAX key derivation (threefry_partitionable semantics)
  uint32_t ks0, ks1, kr0, kr1, kc0, kc1, s10, s11, s20, s21;
  tf2x32(0u, 42u, 0u, 0u, ks0, ks1);
  tf2x32(0u, 42u, 0u, 1u, kr0, kr1);
  tf2x32(0u, 42u, 0u, 2u, kc0, kc1);
  tf2x32(ks0, ks1, 0u, 0u, s10, s11);
  tf2x32(ks0, ks1, 0u, 1u, s20, s21);

  hipMemsetAsync(zbase, 0, zsize, stream);

  const int EB = EDGES / 256;                // 15625
  const int NB = (NNODE + 255) / 256;        // 586

  k_seedsample<<<(NSAMP + 255) / 256, 256, 0, stream>>>(seeds, frontier, masked,
                                                        s10, s11, s20, s21);
  k_bfs0<<<VNB, 256, 0, stream>>>(rows, cols, frontier, alive, nextf, out);
  k_bfs1part<<<DB_NB, 512, 0, stream>>>(rows, cols, nextf, alive, bucketCnt, seg);
  k_degnorm<<<NBUCK, 512, 0, stream>>>(seg, bucketCnt, dnorm, masked, nextf);
  k_enctail<<<ENB, 256, 0, stream>>>(rows, cols, alive, dnorm, out, A, counters);

  // masked node list (ascending) + tem_num — single lookback kernel
  k_mlist<<<MB, 256, 0, stream>>>(masked, mlist, mstate, counters);

  // pairs + self loops + pad; tail already appended compacted
  k_build_pairs<<<EB, 256, 0, stream>>>(mlist, counters, A, kr0, kr1, kc0, kc1);
  k_selfpad<<<NB, 256, 0, stream>>>(A, counters);

  // radix sort: A -> B -> A -> B -> A (4 passes x 9 bits over active chunks)
  unsigned long long* src = A;
  unsigned long long* dst = Bbuf;
  const int shifts[4] = {0, 9, 18, 27};
  for (int p = 0; p < 4; ++p) {
    k_rhist2<<<NC, TH, 0, stream>>>(src, hist, shifts[p], counters);
    k_scan_lb<<<SNT, 256, 0, stream>>>(hist, tstate + (size_t)p * 256);
    k_rscatter2<<<NC, TH, 0, stream>>>(src, dst, hist, shifts[p], counters);
    unsigned long long* t = src; src = dst; dst = t;
  }
  // sorted result now in A (src == A)

  k_uniq_count<<<NTILE, TH, 0, stream>>>(src, uPart, counters);
  k_scan_small<<<1, 1024, 0, stream>>>(uPart, NTILE, counters + 3);
  k_final<<<NTILE, TH, 0, stream>>>(src, uPart, counters, out);
  k_dectail<<<(MOUT / 4 + 255) / 256, 256, 0, stream>>>(counters, out);
}